// Round 9
// baseline (811.749 us; speedup 1.0000x reference)
//
#include <hip/hip_runtime.h>
#include <hip/hip_bf16.h>
#include <cstdint>

#define CDIM 256
#define KNN  16
#define NCHUNK 196   // chunks; grid = 12 slices * NCHUNK = 2352 (2352%8==0)

typedef __attribute__((ext_vector_type(8))) __bf16 bf16x8;
typedef __attribute__((ext_vector_type(4))) float  f4;

__device__ inline ushort f2bf(float f) {
    __bf16 b = (__bf16)f;
    return __builtin_bit_cast(ushort, b);
}
__device__ inline float bf2f(ushort h) {
    return __builtin_bit_cast(float, (unsigned int)h << 16);
}
__device__ inline bf16x8 cvt8(f4 a, f4 b) {
    bf16x8 r;
    r[0] = (__bf16)a[0]; r[1] = (__bf16)a[1]; r[2] = (__bf16)a[2]; r[3] = (__bf16)a[3];
    r[4] = (__bf16)b[0]; r[5] = (__bf16)b[1]; r[6] = (__bf16)b[2]; r[7] = (__bf16)b[3];
    return r;
}

// Weight-in-LDS fused QKV projection (r7 structure, best measured: 182us).
// Wave = 16 feature rows x 64 W-cols; 16-load burst pinned by sched_barrier;
// 3 waves/SIMD hide the batch-head latency. K/V written into interleaved
// [Krow 512B | Vrow 512B] records for the attn fused gather.
__global__ __launch_bounds__(256, 3)
void proj_ldsw(const float* __restrict__ qf, const float* __restrict__ kvf,
               const float* __restrict__ Wq, const float* __restrict__ Wk,
               const float* __restrict__ Wv,
               const float* __restrict__ bq, const float* __restrict__ bk,
               const float* __restrict__ bv, const float* __restrict__ sens,
               float* __restrict__ Qout, ushort* __restrict__ KVout,
               int M, int Npts, int nwg, int ngroups)
{
    __shared__ ushort Wlds[64 * CDIM];   // 32 KB

    // m204 bijective XCD swizzle: the 12 slices of a chunk land on one XCD.
    const int orig = blockIdx.x;
    const int xcd = orig & 7, lin = orig >> 3;
    const int q8 = nwg >> 3, r8 = nwg & 7;
    const int wgid = (xcd < r8 ? xcd * (q8 + 1) : r8 * (q8 + 1) + (xcd - r8) * q8) + lin;
    const int chunk = wgid / 12, matws = wgid % 12;
    const int mat = matws >> 2, ws = matws & 3;

    const int tid  = threadIdx.x;
    const int lane = tid & 63;
    const int wid  = tid >> 6;
    const int l15  = lane & 15, l4 = lane >> 4;
    const int wbase = ws * 64;           // 64 output columns owned by this block

    const float* feat = (mat == 0) ? qf : kvf;
    const float* Wm   = (mat == 0) ? Wq : (mat == 1 ? Wk : Wv);
    const float* bias = (mat == 0) ? bq : (mat == 1 ? bk : bv);

    // ---- stage weight slice: 64 rows x 256 f32 -> bf16 LDS (swizzled) ----
    #pragma unroll
    for (int i = 0; i < 16; i++) {
        int idx = i * 256 + tid;          // f4 index, 4096 total (64 per row)
        int row = idx >> 6, c4 = idx & 63;
        float4 v = *(const float4*)(Wm + (size_t)(wbase + row) * CDIM + c4 * 4);
        ushort4 h;
        h.x = f2bf(v.x); h.y = f2bf(v.y); h.z = f2bf(v.z); h.w = f2bf(v.w);
        *(ushort4*)((char*)Wlds + row * 512 + ((c4 * 8) ^ ((row & 7) << 4))) = h;
    }
    __syncthreads();

    f4 biasf[4];
    #pragma unroll
    for (int mi = 0; mi < 4; mi++)
        biasf[mi] = *(const f4*)(bias + wbase + mi * 16 + l4 * 4);

    // ---- stream m-groups: 64 rows per block, 16 per wave ----
    for (int g = chunk; g < ngroups; g += NCHUNK) {
        const int m0 = g * 64 + wid * 16;
        if (m0 >= M) continue;            // M % 16 == 0: tiles full or absent
        const float* fp = feat + (size_t)m0 * CDIM + (size_t)l15 * CDIM + l4 * 8;

        // batched raw loads: 16 x f4, one burst (16 KB/wave in flight)
        f4 rawA[8], rawB[8];
        #pragma unroll
        for (int ks = 0; ks < 8; ks++) {
            rawA[ks] = *(const f4*)(fp + ks * 32);
            rawB[ks] = *(const f4*)(fp + ks * 32 + 4);
        }
        __builtin_amdgcn_sched_barrier(0);   // nothing sinks past this point

        f4 acc[4];
        #pragma unroll
        for (int mi = 0; mi < 4; mi++) acc[mi] = (f4){0.f, 0.f, 0.f, 0.f};

        #pragma unroll
        for (int ks = 0; ks < 8; ks++) {
            const bf16x8 af = cvt8(rawA[ks], rawB[ks]);
            #pragma unroll
            for (int mi = 0; mi < 4; mi++) {
                const int r = mi * 16 + l15;
                const bf16x8 wfr = *(const bf16x8*)((const char*)Wlds + r * 512
                                      + ((ks * 64 + l4 * 16) ^ ((r & 7) << 4)));
                acc[mi] = __builtin_amdgcn_mfma_f32_16x16x32_bf16(wfr, af, acc[mi], 0, 0, 0);
            }
        }

        // ---- epilogue: D col(lane&15)=feature row m, row=l4*4+reg=W col ----
        const int m = m0 + l15;
        const int nidx = m >= Npts ? m - Npts : m;
        const float sw = (mat == 0) ? 1.f : sens[nidx];
        #pragma unroll
        for (int mi = 0; mi < 4; mi++) {
            const int wr0 = wbase + mi * 16 + l4 * 4;
            f4 v = acc[mi] + biasf[mi];
            if (mat == 0) {
                __builtin_nontemporal_store(v, (f4*)(Qout + (size_t)m * CDIM + wr0));
            } else {
                v *= sw;
                ushort4 h;
                h.x = f2bf(v[0]); h.y = f2bf(v[1]);
                h.z = f2bf(v[2]); h.w = f2bf(v[3]);
                // interleaved KV record: [Krow 512B | Vrow 512B] per point
                *(ushort4*)(KVout + (size_t)m * 512 + (mat == 2 ? 256 : 0) + wr0) = h;
            }
        }
    }
}

// One wave per point. ONE dwordx4 gather per (point, neighbor): lanes 0-31
// read the K-half of the 1KB record, lanes 32-63 the V-half (offset = lane*16,
// fully linear). Halves gather transactions 32 -> 16 per point. Dot reduces
// on the lower half; logits broadcast via shfl; PV/residual/LN on upper half.
__global__ __launch_bounds__(256, 4)
void attn_ln_bf(float* __restrict__ QO, const ushort* __restrict__ KV,
                const int* __restrict__ knn,
                const float* __restrict__ ln_g, const float* __restrict__ ln_b,
                int Ntot, int Npts)
{
    const int w = blockIdx.x * 4 + (threadIdx.x >> 6);
    if (w >= Ntot) return;
    const int lane = threadIdx.x & 63;
    const int half = lane >> 5;          // 0 = K-half, 1 = V-half
    const int p    = lane & 31;          // channel group: ch 8p..8p+7
    const int n    = w >= Npts ? w - Npts : w;
    const int rb   = w >= Npts ? Npts : 0;

    // q channels 8p..8p+7 on BOTH halves (same addrs -> one HBM fetch)
    const float* qp = QO + (size_t)w * CDIM + p * 8;
    const f4 qa = __builtin_nontemporal_load((const f4*)qp);
    const f4 qb = __builtin_nontemporal_load((const f4*)(qp + 4));

    const int ns = __builtin_amdgcn_readfirstlane(n);
    const int* ki = knn + ns * KNN;
    int idxs[KNN];
    #pragma unroll
    for (int j = 0; j < KNN; j++) idxs[j] = ki[j];

    // fused record gathers: 16B/lane, 1KB contiguous per wave per neighbor
    bf16x8 rec[KNN];
    #pragma unroll
    for (int j = 0; j < KNN; j++)
        rec[j] = *(const bf16x8*)((const char*)(KV + (size_t)(rb + idxs[j]) * 512)
                                  + (size_t)lane * 16);

    // dot: lower half computes q.K partials (upper computes garbage, unused)
    float d[KNN];
    #pragma unroll
    for (int j = 0; j < KNN; j++) {
        f4 k0, k1;
        #pragma unroll
        for (int i = 0; i < 4; i++) { k0[i] = (float)rec[j][i]; k1[i] = (float)rec[j][i + 4]; }
        d[j] = qa[0]*k0[0] + qa[1]*k0[1] + qa[2]*k0[2] + qa[3]*k0[3]
             + qb[0]*k1[0] + qb[1]*k1[1] + qb[2]*k1[2] + qb[3]*k1[3];
    }
    #pragma unroll
    for (int m = 1; m < 32; m <<= 1) {   // in-half reduce
        #pragma unroll
        for (int j = 0; j < KNN; j++) d[j] += __shfl_xor(d[j], m, 64);
    }
    #pragma unroll
    for (int j = 0; j < KNN; j++) d[j] = __shfl(d[j], p, 64);  // lower -> both halves

    float mx = -1e30f;
    #pragma unroll
    for (int j = 0; j < KNN; j++) { d[j] *= 0.0625f; mx = fmaxf(mx, d[j]); }
    float s = 0.f;
    #pragma unroll
    for (int j = 0; j < KNN; j++) { d[j] = __expf(d[j] - mx); s += d[j]; }
    const float inv = 1.f / s;

    // PV: upper half has V channels 8p..8p+7 in rec[j]
    f4 oa = (f4){0.f, 0.f, 0.f, 0.f}, ob = (f4){0.f, 0.f, 0.f, 0.f};
    #pragma unroll
    for (int j = 0; j < KNN; j++) {
        const float pj = d[j] * inv;
        #pragma unroll
        for (int i = 0; i < 4; i++) {
            oa[i] += pj * (float)rec[j][i];
            ob[i] += pj * (float)rec[j][i + 4];
        }
    }

    // residual + LayerNorm on the upper half (8 channels per lane)
    f4 xa = oa + qa, xb = ob + qb;
    float ssum = xa[0]+xa[1]+xa[2]+xa[3]+xb[0]+xb[1]+xb[2]+xb[3];
    #pragma unroll
    for (int m = 1; m < 32; m <<= 1) ssum += __shfl_xor(ssum, m, 64);
    const float mu = ssum * (1.f / 256.f);

    f4 ea, eb;
    #pragma unroll
    for (int i = 0; i < 4; i++) { ea[i] = xa[i] - mu; eb[i] = xb[i] - mu; }
    float vsum = ea[0]*ea[0]+ea[1]*ea[1]+ea[2]*ea[2]+ea[3]*ea[3]
               + eb[0]*eb[0]+eb[1]*eb[1]+eb[2]*eb[2]+eb[3]*eb[3];
    #pragma unroll
    for (int m = 1; m < 32; m <<= 1) vsum += __shfl_xor(vsum, m, 64);
    const float rstd = rsqrtf(vsum * (1.f / 256.f) + 1e-5f);

    const float* gp = ln_g + p * 8;
    const float* bp = ln_b + p * 8;
    const f4 ga = *(const f4*)gp,       gb2 = *(const f4*)(gp + 4);
    const f4 ba = *(const f4*)bp,       bb2 = *(const f4*)(bp + 4);
    f4 outa, outb;
    #pragma unroll
    for (int i = 0; i < 4; i++) {
        outa[i] = ea[i] * rstd * ga[i] + ba[i];
        outb[i] = eb[i] * rstd * gb2[i] + bb2[i];
    }
    if (half) {
        float* op = QO + (size_t)w * CDIM + p * 8;
        __builtin_nontemporal_store(outa, (f4*)op);
        __builtin_nontemporal_store(outb, (f4*)(op + 4));
    }
}

extern "C" void kernel_launch(void* const* d_in, const int* in_sizes, int n_in,
                              void* d_out, int out_size, void* d_ws, size_t ws_size,
                              hipStream_t stream)
{
    const float* q_feat  = (const float*)d_in[0];
    const float* kv_feat = (const float*)d_in[1];
    const int*   knn     = (const int*)d_in[2];
    const float* sens    = (const float*)d_in[3];
    const float* Wq_w    = (const float*)d_in[4];
    const float* Wq_b    = (const float*)d_in[5];
    const float* Wk_w    = (const float*)d_in[6];
    const float* Wk_b    = (const float*)d_in[7];
    const float* Wv_w    = (const float*)d_in[8];
    const float* Wv_b    = (const float*)d_in[9];
    const float* ln_g    = (const float*)d_in[10];
    const float* ln_b    = (const float*)d_in[11];

    const int Npts = in_sizes[3];              // N = 50000
    const int M    = in_sizes[0] / CDIM;       // B*N = 100000
    const int ngroups = (M + 63) / 64;         // 1563

    ushort* KVtb = (ushort*)d_ws;              // [M] records of 1KB

    const int nwg = 12 * NCHUNK;               // 2352 blocks
    proj_ldsw<<<nwg, 256, 0, stream>>>(q_feat, kv_feat, Wq_w, Wk_w, Wv_w,
                                       Wq_b, Wk_b, Wv_b, sens,
                                       (float*)d_out, KVtb,
                                       M, Npts, nwg, ngroups);

    attn_ln_bf<<<(M + 3) / 4, 256, 0, stream>>>((float*)d_out, KVtb, knn,
                                                ln_g, ln_b, M, Npts);
}

// Round 10
// 441.388 us; speedup vs baseline: 1.8391x; 1.8391x over previous
//
#include <hip/hip_runtime.h>
#include <hip/hip_bf16.h>
#include <cstdint>

#define CDIM 256
#define KNN  16
#define NCHUNK 104   // grid = 12 * 104 = 1248 blocks (%8==0), all-resident at 5/CU

typedef __attribute__((ext_vector_type(8))) __bf16 bf16x8;
typedef __attribute__((ext_vector_type(4))) float  f4;

__device__ inline ushort f2bf(float f) {
    __bf16 b = (__bf16)f;
    return __builtin_bit_cast(ushort, b);
}
__device__ inline float bf2f(ushort h) {
    return __builtin_bit_cast(float, (unsigned int)h << 16);
}
__device__ inline bf16x8 cvt8(f4 a, f4 b) {
    bf16x8 r;
    r[0] = (__bf16)a[0]; r[1] = (__bf16)a[1]; r[2] = (__bf16)a[2]; r[3] = (__bf16)a[3];
    r[4] = (__bf16)b[0]; r[5] = (__bf16)b[1]; r[6] = (__bf16)b[2]; r[7] = (__bf16)b[3];
    return r;
}

// Weight-in-LDS fused QKV projection (r7 structure; this round: 5 blocks/CU).
// Wave = 16 feature rows x 64 W-cols; 16-load burst pinned by sched_barrier;
// latency hidden by occupancy (proj is latency-bound: r6->r7 scaled ~1/occ).
__global__ __launch_bounds__(256, 5)
void proj_ldsw(const float* __restrict__ qf, const float* __restrict__ kvf,
               const float* __restrict__ Wq, const float* __restrict__ Wk,
               const float* __restrict__ Wv,
               const float* __restrict__ bq, const float* __restrict__ bk,
               const float* __restrict__ bv, const float* __restrict__ sens,
               float* __restrict__ Qout, ushort* __restrict__ KVout,
               int M, int Npts, int nwg, int ngroups)
{
    __shared__ ushort Wlds[64 * CDIM];   // 32 KB -> 5 blocks/CU = 160 KB exactly

    // m204 bijective XCD swizzle: the 12 slices of a chunk land on one XCD.
    const int orig = blockIdx.x;
    const int xcd = orig & 7, lin = orig >> 3;
    const int q8 = nwg >> 3, r8 = nwg & 7;
    const int wgid = (xcd < r8 ? xcd * (q8 + 1) : r8 * (q8 + 1) + (xcd - r8) * q8) + lin;
    const int chunk = wgid / 12, matws = wgid % 12;
    const int mat = matws >> 2, ws = matws & 3;

    const int tid  = threadIdx.x;
    const int lane = tid & 63;
    const int wid  = tid >> 6;
    const int l15  = lane & 15, l4 = lane >> 4;
    const int wbase = ws * 64;           // 64 output columns owned by this block

    const float* feat = (mat == 0) ? qf : kvf;
    const float* Wm   = (mat == 0) ? Wq : (mat == 1 ? Wk : Wv);
    const float* bias = (mat == 0) ? bq : (mat == 1 ? bk : bv);

    // ---- stage weight slice: 64 rows x 256 f32 -> bf16 LDS (swizzled) ----
    #pragma unroll
    for (int i = 0; i < 16; i++) {
        int idx = i * 256 + tid;          // f4 index, 4096 total (64 per row)
        int row = idx >> 6, c4 = idx & 63;
        float4 v = *(const float4*)(Wm + (size_t)(wbase + row) * CDIM + c4 * 4);
        ushort4 h;
        h.x = f2bf(v.x); h.y = f2bf(v.y); h.z = f2bf(v.z); h.w = f2bf(v.w);
        *(ushort4*)((char*)Wlds + row * 512 + ((c4 * 8) ^ ((row & 7) << 4))) = h;
    }
    __syncthreads();

    f4 biasf[4];
    #pragma unroll
    for (int mi = 0; mi < 4; mi++)
        biasf[mi] = *(const f4*)(bias + wbase + mi * 16 + l4 * 4);

    // ---- stream m-groups: 64 rows per block, 16 per wave ----
    for (int g = chunk; g < ngroups; g += NCHUNK) {
        const int m0 = g * 64 + wid * 16;
        if (m0 >= M) continue;            // M % 16 == 0: tiles full or absent
        const float* fp = feat + (size_t)m0 * CDIM + (size_t)l15 * CDIM + l4 * 8;

        // batched raw loads: 16 x f4, one burst (16 KB/wave in flight)
        f4 rawA[8], rawB[8];
        #pragma unroll
        for (int ks = 0; ks < 8; ks++) {
            rawA[ks] = *(const f4*)(fp + ks * 32);
            rawB[ks] = *(const f4*)(fp + ks * 32 + 4);
        }
        __builtin_amdgcn_sched_barrier(0);   // nothing sinks past this point

        f4 acc[4];
        #pragma unroll
        for (int mi = 0; mi < 4; mi++) acc[mi] = (f4){0.f, 0.f, 0.f, 0.f};

        #pragma unroll
        for (int ks = 0; ks < 8; ks++) {
            const bf16x8 af = cvt8(rawA[ks], rawB[ks]);
            #pragma unroll
            for (int mi = 0; mi < 4; mi++) {
                const int r = mi * 16 + l15;
                const bf16x8 wfr = *(const bf16x8*)((const char*)Wlds + r * 512
                                      + ((ks * 64 + l4 * 16) ^ ((r & 7) << 4)));
                acc[mi] = __builtin_amdgcn_mfma_f32_16x16x32_bf16(wfr, af, acc[mi], 0, 0, 0);
            }
        }

        // ---- epilogue: D col(lane&15)=feature row m, row=l4*4+reg=W col ----
        const int m = m0 + l15;
        const int nidx = m >= Npts ? m - Npts : m;
        const float sw = (mat == 0) ? 1.f : sens[nidx];
        #pragma unroll
        for (int mi = 0; mi < 4; mi++) {
            const int wr0 = wbase + mi * 16 + l4 * 4;
            f4 v = acc[mi] + biasf[mi];
            if (mat == 0) {
                __builtin_nontemporal_store(v, (f4*)(Qout + (size_t)m * CDIM + wr0));
            } else {
                v *= sw;
                ushort4 h;
                h.x = f2bf(v[0]); h.y = f2bf(v[1]);
                h.z = f2bf(v[2]); h.w = f2bf(v[3]);
                // interleaved KV record: [Krow 512B | Vrow 512B] per point
                *(ushort4*)(KVout + (size_t)m * 512 + (mat == 2 ? 256 : 0) + wr0) = h;
            }
        }
    }
}

// One wave per point: gathered 16-NN attention from interleaved KV records,
// r8 shape (measured best: 236 us): two dwordx2 gathers per record.
__global__ __launch_bounds__(256, 4)
void attn_ln_bf(float* __restrict__ QO, const ushort* __restrict__ KV,
                const int* __restrict__ knn,
                const float* __restrict__ ln_g, const float* __restrict__ ln_b,
                int Ntot, int Npts)
{
    const int w = blockIdx.x * 4 + (threadIdx.x >> 6);
    if (w >= Ntot) return;
    const int lane = threadIdx.x & 63;
    const int n    = w >= Npts ? w - Npts : w;
    const int rb   = w >= Npts ? Npts : 0;      // record-base for this batch

    const f4 q = __builtin_nontemporal_load(
        (const f4*)(QO + (size_t)w * CDIM + lane * 4));

    const int ns = __builtin_amdgcn_readfirstlane(n);
    const int* ki = knn + ns * KNN;
    int idxs[KNN];
    #pragma unroll
    for (int j = 0; j < KNN; j++) idxs[j] = ki[j];

    // batched gathers, K/V adjacent per record
    ushort4 kr[KNN], vr[KNN];
    #pragma unroll
    for (int j = 0; j < KNN; j++) {
        const ushort* rec = KV + (size_t)(rb + idxs[j]) * 512;
        kr[j] = *(const ushort4*)(rec + lane * 4);
        vr[j] = *(const ushort4*)(rec + 256 + lane * 4);
    }

    float d[KNN];
    #pragma unroll
    for (int j = 0; j < KNN; j++)
        d[j] = q[0] * bf2f(kr[j].x) + q[1] * bf2f(kr[j].y)
             + q[2] * bf2f(kr[j].z) + q[3] * bf2f(kr[j].w);

    #pragma unroll
    for (int m = 1; m < 64; m <<= 1) {
        #pragma unroll
        for (int j = 0; j < KNN; j++) d[j] += __shfl_xor(d[j], m, 64);
    }

    float mx = -1e30f;
    #pragma unroll
    for (int j = 0; j < KNN; j++) { d[j] *= 0.0625f; mx = fmaxf(mx, d[j]); }
    float s = 0.f;
    #pragma unroll
    for (int j = 0; j < KNN; j++) { d[j] = __expf(d[j] - mx); s += d[j]; }
    const float inv = 1.f / s;

    f4 o = (f4){0.f, 0.f, 0.f, 0.f};
    #pragma unroll
    for (int j = 0; j < KNN; j++) {
        const float pj = d[j] * inv;
        o[0] += pj * bf2f(vr[j].x); o[1] += pj * bf2f(vr[j].y);
        o[2] += pj * bf2f(vr[j].z); o[3] += pj * bf2f(vr[j].w);
    }

    f4 x = o + q;

    float ssum = x[0] + x[1] + x[2] + x[3];
    #pragma unroll
    for (int m = 1; m < 64; m <<= 1) ssum += __shfl_xor(ssum, m, 64);
    const float mu = ssum * (1.f / 256.f);

    f4 e;
    e[0] = x[0] - mu; e[1] = x[1] - mu; e[2] = x[2] - mu; e[3] = x[3] - mu;
    float vsum = e[0] * e[0] + e[1] * e[1] + e[2] * e[2] + e[3] * e[3];
    #pragma unroll
    for (int m = 1; m < 64; m <<= 1) vsum += __shfl_xor(vsum, m, 64);
    const float rstd = rsqrtf(vsum * (1.f / 256.f) + 1e-5f);

    const f4 g  = *(const f4*)(ln_g + lane * 4);
    const f4 bb = *(const f4*)(ln_b + lane * 4);
    f4 outv;
    outv[0] = e[0] * rstd * g[0] + bb[0];
    outv[1] = e[1] * rstd * g[1] + bb[1];
    outv[2] = e[2] * rstd * g[2] + bb[2];
    outv[3] = e[3] * rstd * g[3] + bb[3];
    __builtin_nontemporal_store(outv, (f4*)(QO + (size_t)w * CDIM + lane * 4));
}

extern "C" void kernel_launch(void* const* d_in, const int* in_sizes, int n_in,
                              void* d_out, int out_size, void* d_ws, size_t ws_size,
                              hipStream_t stream)
{
    const float* q_feat  = (const float*)d_in[0];
    const float* kv_feat = (const float*)d_in[1];
    const int*   knn     = (const int*)d_in[2];
    const float* sens    = (const float*)d_in[3];
    const float* Wq_w    = (const float*)d_in[4];
    const float* Wq_b    = (const float*)d_in[5];
    const float* Wk_w    = (const float*)d_in[6];
    const float* Wk_b    = (const float*)d_in[7];
    const float* Wv_w    = (const float*)d_in[8];
    const float* Wv_b    = (const float*)d_in[9];
    const float* ln_g    = (const float*)d_in[10];
    const float* ln_b    = (const float*)d_in[11];

    const int Npts = in_sizes[3];              // N = 50000
    const int M    = in_sizes[0] / CDIM;       // B*N = 100000
    const int ngroups = (M + 63) / 64;         // 1563

    ushort* KVtb = (ushort*)d_ws;              // [M] records of 1KB

    const int nwg = 12 * NCHUNK;               // 1248 blocks
    proj_ldsw<<<nwg, 256, 0, stream>>>(q_feat, kv_feat, Wq_w, Wk_w, Wv_w,
                                       Wq_b, Wk_b, Wv_b, sens,
                                       (float*)d_out, KVtb,
                                       M, Npts, nwg, ngroups);

    attn_ln_bf<<<(M + 3) / 4, 256, 0, stream>>>((float*)d_out, KVtb, knn,
                                                ln_g, ln_b, M, Npts);
}

// Round 11
// 413.113 us; speedup vs baseline: 1.9650x; 1.0684x over previous
//
#include <hip/hip_runtime.h>
#include <hip/hip_bf16.h>
#include <cstdint>

#define CDIM 256
#define KNN  16
#define NCQ  96     // Q-chunk stride
#define NCKV 192    // KV-chunk stride; grid = 4*NCQ + 4*NCKV = 1152 (%8==0)

typedef __attribute__((ext_vector_type(8))) __bf16 bf16x8;
typedef __attribute__((ext_vector_type(4))) float  f4;

__device__ inline ushort f2bf(float f) {
    __bf16 b = (__bf16)f;
    return __builtin_bit_cast(ushort, b);
}
__device__ inline float bf2f(ushort h) {
    return __builtin_bit_cast(float, (unsigned int)h << 16);
}
__device__ inline bf16x8 cvt8(f4 a, f4 b) {
    bf16x8 r;
    r[0] = (__bf16)a[0]; r[1] = (__bf16)a[1]; r[2] = (__bf16)a[2]; r[3] = (__bf16)a[3];
    r[4] = (__bf16)b[0]; r[5] = (__bf16)b[1]; r[6] = (__bf16)b[2]; r[7] = (__bf16)b[3];
    return r;
}
__device__ inline ushort4 packbf(f4 v) {
    ushort4 h;
    h.x = f2bf(v[0]); h.y = f2bf(v[1]); h.z = f2bf(v[2]); h.w = f2bf(v[3]);
    return h;
}

// Fused QKV projection. Q-blocks: r7 structure (1 W slice, 32 KB). KV-blocks:
// stage BOTH Wk and Wv slices (64 KB) and run two MFMA chains per A-burst --
// doubles compute-per-burst (latency cover) and halves kv_feat re-reads.
// Q written bf16. K/V written into interleaved [K 512B | V 512B] records.
__global__ __launch_bounds__(256, 2)
void proj_qkv(const float* __restrict__ qf, const float* __restrict__ kvf,
              const float* __restrict__ Wq, const float* __restrict__ Wk,
              const float* __restrict__ Wv,
              const float* __restrict__ bq, const float* __restrict__ bk,
              const float* __restrict__ bv, const float* __restrict__ sens,
              ushort* __restrict__ Qout, ushort* __restrict__ KVout,
              int M, int Npts, int nwg, int ngroups)
{
    __shared__ ushort Wlds[2][64 * CDIM];   // 64 KB (Q-blocks use [0] only)

    // m204 bijective XCD swizzle (nwg%8==0 -> wgid = xcd*q8 + lin); the 4
    // slices of a chunk stay contiguous -> same XCD L2.
    const int orig = blockIdx.x;
    const int xcd = orig & 7, lin = orig >> 3;
    const int q8 = nwg >> 3;
    const int wgid = xcd * q8 + lin;

    const bool isQ = wgid < 4 * NCQ;
    const int t = isQ ? wgid : wgid - 4 * NCQ;
    const int chunk = t >> 2, ws = t & 3;

    const int tid  = threadIdx.x;
    const int lane = tid & 63;
    const int wid  = tid >> 6;
    const int l15  = lane & 15, l4 = lane >> 4;
    const int wbase = ws * 64;

    auto stageW = [&](const float* Wm, ushort* dst) {
        #pragma unroll
        for (int i = 0; i < 16; i++) {
            int idx = i * 256 + tid;
            int row = idx >> 6, c4 = idx & 63;
            float4 v = *(const float4*)(Wm + (size_t)(wbase + row) * CDIM + c4 * 4);
            ushort4 h;
            h.x = f2bf(v.x); h.y = f2bf(v.y); h.z = f2bf(v.z); h.w = f2bf(v.w);
            *(ushort4*)((char*)dst + row * 512 + ((c4 * 8) ^ ((row & 7) << 4))) = h;
        }
    };
    if (isQ) {
        stageW(Wq, &Wlds[0][0]);
    } else {
        stageW(Wk, &Wlds[0][0]);
        stageW(Wv, &Wlds[1][0]);
    }
    __syncthreads();

    if (isQ) {
        f4 biasf[4];
        #pragma unroll
        for (int mi = 0; mi < 4; mi++)
            biasf[mi] = *(const f4*)(bq + wbase + mi * 16 + l4 * 4);

        for (int g = chunk; g < ngroups; g += NCQ) {
            const int m0 = g * 64 + wid * 16;
            if (m0 >= M) continue;
            const float* fp = qf + (size_t)m0 * CDIM + (size_t)l15 * CDIM + l4 * 8;

            f4 rawA[8], rawB[8];
            #pragma unroll
            for (int ks = 0; ks < 8; ks++) {
                rawA[ks] = *(const f4*)(fp + ks * 32);
                rawB[ks] = *(const f4*)(fp + ks * 32 + 4);
            }
            __builtin_amdgcn_sched_barrier(0);

            f4 acc[4];
            #pragma unroll
            for (int mi = 0; mi < 4; mi++) acc[mi] = (f4){0.f, 0.f, 0.f, 0.f};
            #pragma unroll
            for (int ks = 0; ks < 8; ks++) {
                const bf16x8 af = cvt8(rawA[ks], rawB[ks]);
                #pragma unroll
                for (int mi = 0; mi < 4; mi++) {
                    const int r = mi * 16 + l15;
                    const bf16x8 wfr = *(const bf16x8*)((const char*)&Wlds[0][0] + r * 512
                                          + ((ks * 64 + l4 * 16) ^ ((r & 7) << 4)));
                    acc[mi] = __builtin_amdgcn_mfma_f32_16x16x32_bf16(wfr, af, acc[mi], 0, 0, 0);
                }
            }

            const int m = m0 + l15;
            #pragma unroll
            for (int mi = 0; mi < 4; mi++) {
                const int wr0 = wbase + mi * 16 + l4 * 4;
                *(ushort4*)(Qout + (size_t)m * CDIM + wr0) = packbf(acc[mi] + biasf[mi]);
            }
        }
    } else {
        f4 biasK[4], biasV[4];
        #pragma unroll
        for (int mi = 0; mi < 4; mi++) {
            biasK[mi] = *(const f4*)(bk + wbase + mi * 16 + l4 * 4);
            biasV[mi] = *(const f4*)(bv + wbase + mi * 16 + l4 * 4);
        }

        for (int g = chunk; g < ngroups; g += NCKV) {
            const int m0 = g * 64 + wid * 16;
            if (m0 >= M) continue;
            const float* fp = kvf + (size_t)m0 * CDIM + (size_t)l15 * CDIM + l4 * 8;

            f4 rawA[8], rawB[8];
            #pragma unroll
            for (int ks = 0; ks < 8; ks++) {
                rawA[ks] = *(const f4*)(fp + ks * 32);
                rawB[ks] = *(const f4*)(fp + ks * 32 + 4);
            }
            __builtin_amdgcn_sched_barrier(0);

            f4 accK[4], accV[4];
            #pragma unroll
            for (int mi = 0; mi < 4; mi++) {
                accK[mi] = (f4){0.f, 0.f, 0.f, 0.f};
                accV[mi] = (f4){0.f, 0.f, 0.f, 0.f};
            }
            #pragma unroll
            for (int ks = 0; ks < 8; ks++) {
                const bf16x8 af = cvt8(rawA[ks], rawB[ks]);
                #pragma unroll
                for (int mi = 0; mi < 4; mi++) {
                    const int r = mi * 16 + l15;
                    const int cb = (ks * 64 + l4 * 16) ^ ((r & 7) << 4);
                    const bf16x8 wk = *(const bf16x8*)((const char*)&Wlds[0][0] + r * 512 + cb);
                    accK[mi] = __builtin_amdgcn_mfma_f32_16x16x32_bf16(wk, af, accK[mi], 0, 0, 0);
                    const bf16x8 wv = *(const bf16x8*)((const char*)&Wlds[1][0] + r * 512 + cb);
                    accV[mi] = __builtin_amdgcn_mfma_f32_16x16x32_bf16(wv, af, accV[mi], 0, 0, 0);
                }
            }

            const int m = m0 + l15;
            const int nidx = m >= Npts ? m - Npts : m;
            const float sw = sens[nidx];
            #pragma unroll
            for (int mi = 0; mi < 4; mi++) {
                const int wr0 = wbase + mi * 16 + l4 * 4;
                f4 vk = (accK[mi] + biasK[mi]) * sw;
                f4 vv = (accV[mi] + biasV[mi]) * sw;
                *(ushort4*)(KVout + (size_t)m * 512 + wr0)       = packbf(vk);
                *(ushort4*)(KVout + (size_t)m * 512 + 256 + wr0) = packbf(vv);
            }
        }
    }
}

// One wave per point (r8 shape, measured best). Batch-split: one dispatch per
// batch so the 51 MB per-batch KV gather set better survives in L3.
__global__ __launch_bounds__(256, 4)
void attn_ln_bf(const ushort* __restrict__ Qb, float* __restrict__ Out,
                const ushort* __restrict__ KV, const int* __restrict__ knn,
                const float* __restrict__ ln_g, const float* __restrict__ ln_b,
                int Npts, int base)
{
    const int n = blockIdx.x * 4 + (threadIdx.x >> 6);
    if (n >= Npts) return;
    const int lane = threadIdx.x & 63;
    const size_t row = (size_t)(base + n);

    ushort4 qh = *(const ushort4*)(Qb + row * CDIM + lane * 4);
    f4 q;
    q[0] = bf2f(qh.x); q[1] = bf2f(qh.y); q[2] = bf2f(qh.z); q[3] = bf2f(qh.w);

    const int ns = __builtin_amdgcn_readfirstlane(n);
    const int* ki = knn + ns * KNN;
    int idxs[KNN];
    #pragma unroll
    for (int j = 0; j < KNN; j++) idxs[j] = ki[j];

    ushort4 kr[KNN], vr[KNN];
    #pragma unroll
    for (int j = 0; j < KNN; j++) {
        const ushort* rec = KV + (size_t)(base + idxs[j]) * 512;
        kr[j] = *(const ushort4*)(rec + lane * 4);
        vr[j] = *(const ushort4*)(rec + 256 + lane * 4);
    }

    float d[KNN];
    #pragma unroll
    for (int j = 0; j < KNN; j++)
        d[j] = q[0] * bf2f(kr[j].x) + q[1] * bf2f(kr[j].y)
             + q[2] * bf2f(kr[j].z) + q[3] * bf2f(kr[j].w);

    #pragma unroll
    for (int m = 1; m < 64; m <<= 1) {
        #pragma unroll
        for (int j = 0; j < KNN; j++) d[j] += __shfl_xor(d[j], m, 64);
    }

    float mx = -1e30f;
    #pragma unroll
    for (int j = 0; j < KNN; j++) { d[j] *= 0.0625f; mx = fmaxf(mx, d[j]); }
    float s = 0.f;
    #pragma unroll
    for (int j = 0; j < KNN; j++) { d[j] = __expf(d[j] - mx); s += d[j]; }
    const float inv = 1.f / s;

    f4 o = (f4){0.f, 0.f, 0.f, 0.f};
    #pragma unroll
    for (int j = 0; j < KNN; j++) {
        const float pj = d[j] * inv;
        o[0] += pj * bf2f(vr[j].x); o[1] += pj * bf2f(vr[j].y);
        o[2] += pj * bf2f(vr[j].z); o[3] += pj * bf2f(vr[j].w);
    }

    f4 x = o + q;

    float ssum = x[0] + x[1] + x[2] + x[3];
    #pragma unroll
    for (int m = 1; m < 64; m <<= 1) ssum += __shfl_xor(ssum, m, 64);
    const float mu = ssum * (1.f / 256.f);

    f4 e;
    e[0] = x[0] - mu; e[1] = x[1] - mu; e[2] = x[2] - mu; e[3] = x[3] - mu;
    float vsum = e[0] * e[0] + e[1] * e[1] + e[2] * e[2] + e[3] * e[3];
    #pragma unroll
    for (int m = 1; m < 64; m <<= 1) vsum += __shfl_xor(vsum, m, 64);
    const float rstd = rsqrtf(vsum * (1.f / 256.f) + 1e-5f);

    const f4 g  = *(const f4*)(ln_g + lane * 4);
    const f4 bb = *(const f4*)(ln_b + lane * 4);
    f4 outv;
    outv[0] = e[0] * rstd * g[0] + bb[0];
    outv[1] = e[1] * rstd * g[1] + bb[1];
    outv[2] = e[2] * rstd * g[2] + bb[2];
    outv[3] = e[3] * rstd * g[3] + bb[3];
    __builtin_nontemporal_store(outv, (f4*)(Out + row * CDIM + lane * 4));
}

extern "C" void kernel_launch(void* const* d_in, const int* in_sizes, int n_in,
                              void* d_out, int out_size, void* d_ws, size_t ws_size,
                              hipStream_t stream)
{
    const float* q_feat  = (const float*)d_in[0];
    const float* kv_feat = (const float*)d_in[1];
    const int*   knn     = (const int*)d_in[2];
    const float* sens    = (const float*)d_in[3];
    const float* Wq_w    = (const float*)d_in[4];
    const float* Wq_b    = (const float*)d_in[5];
    const float* Wk_w    = (const float*)d_in[6];
    const float* Wk_b    = (const float*)d_in[7];
    const float* Wv_w    = (const float*)d_in[8];
    const float* Wv_b    = (const float*)d_in[9];
    const float* ln_g    = (const float*)d_in[10];
    const float* ln_b    = (const float*)d_in[11];

    const int Npts = in_sizes[3];              // N = 50000
    const int M    = in_sizes[0] / CDIM;       // B*N = 100000
    const int ngroups = (M + 63) / 64;         // 1563

    ushort* Qb   = (ushort*)d_ws;              // [M][256] bf16   (51.2 MB)
    ushort* KVtb = Qb + (size_t)M * CDIM;      // [M] 1KB records (102.4 MB)

    const int nwg = 4 * NCQ + 4 * NCKV;        // 1152 blocks
    proj_qkv<<<nwg, 256, 0, stream>>>(q_feat, kv_feat, Wq_w, Wk_w, Wv_w,
                                      Wq_b, Wk_b, Wv_b, sens,
                                      Qb, KVtb, M, Npts, nwg, ngroups);

    const int nattn = (Npts + 3) / 4;
    attn_ln_bf<<<nattn, 256, 0, stream>>>(Qb, (float*)d_out, KVtb, knn,
                                          ln_g, ln_b, Npts, 0);
    attn_ln_bf<<<nattn, 256, 0, stream>>>(Qb, (float*)d_out, KVtb, knn,
                                          ln_g, ln_b, Npts, Npts);
}

// Round 12
// 392.612 us; speedup vs baseline: 2.0676x; 1.0522x over previous
//
#include <hip/hip_runtime.h>
#include <hip/hip_bf16.h>
#include <cstdint>

#define CDIM 256
#define KNN  16
#define NCQ  128    // Q chunks:  grid 4*128 = 512 blocks (2/CU, all resident)
#define NCKV 64     // KV chunks: grid 4*64  = 256 blocks (1/CU, all resident)

typedef __attribute__((ext_vector_type(8))) __bf16 bf16x8;
typedef __attribute__((ext_vector_type(4))) float  f4;

__device__ inline ushort f2bf(float f) {
    __bf16 b = (__bf16)f;
    return __builtin_bit_cast(ushort, b);
}
__device__ inline float bf2f(ushort h) {
    return __builtin_bit_cast(float, (unsigned int)h << 16);
}
__device__ inline bf16x8 cvt8(f4 a, f4 b) {
    bf16x8 r;
    r[0] = (__bf16)a[0]; r[1] = (__bf16)a[1]; r[2] = (__bf16)a[2]; r[3] = (__bf16)a[3];
    r[4] = (__bf16)b[0]; r[5] = (__bf16)b[1]; r[6] = (__bf16)b[2]; r[7] = (__bf16)b[3];
    return r;
}
__device__ inline ushort4 packbf(f4 v) {
    ushort4 h;
    h.x = f2bf(v[0]); h.y = f2bf(v[1]); h.z = f2bf(v[2]); h.w = f2bf(v[3]);
    return h;
}

// stage a 64-row x 256-col f32 weight slice -> bf16 LDS, XOR-swizzled.
// 1024 threads: 4 f4 elements each.
__device__ inline void stage_w(const float* Wm, int wbase, ushort* dst, int tid) {
    #pragma unroll
    for (int i = 0; i < 4; i++) {
        int idx = i * 1024 + tid;
        int row = idx >> 6, c4 = idx & 63;
        float4 v = *(const float4*)(Wm + (size_t)(wbase + row) * CDIM + c4 * 4);
        ushort4 h;
        h.x = f2bf(v.x); h.y = f2bf(v.y); h.z = f2bf(v.z); h.w = f2bf(v.w);
        *(ushort4*)((char*)dst + row * 512 + ((c4 * 8) ^ ((row & 7) << 4))) = h;
    }
}

// Q projection: 16-wave blocks, one 32 KB Wq slice. Wave = 16 rows x 64 cols.
// 16-load burst pinned by sched_barrier; 16 waves/block give 4-8 waves/SIMD.
__global__ __launch_bounds__(1024, 4)
void proj_q(const float* __restrict__ qf, const float* __restrict__ Wq,
            const float* __restrict__ bq, ushort* __restrict__ Qout,
            int M, int nwg, int ngroups)
{
    __shared__ ushort Wlds[64 * CDIM];   // 32 KB

    const int orig = blockIdx.x;
    const int xcd = orig & 7, lin = orig >> 3;
    const int wgid = xcd * (nwg >> 3) + lin;       // nwg % 8 == 0
    const int chunk = wgid >> 2, ws = wgid & 3;

    const int tid  = threadIdx.x;
    const int lane = tid & 63;
    const int wid  = tid >> 6;                     // 0..15
    const int l15  = lane & 15, l4 = lane >> 4;
    const int wbase = ws * 64;

    stage_w(Wq, wbase, Wlds, tid);
    __syncthreads();

    f4 biasf[4];
    #pragma unroll
    for (int mi = 0; mi < 4; mi++)
        biasf[mi] = *(const f4*)(bq + wbase + mi * 16 + l4 * 4);

    for (int g = chunk; g < ngroups; g += NCQ) {
        const int m0 = g * 256 + wid * 16;
        if (m0 >= M) continue;                     // M % 16 == 0
        const float* fp = qf + (size_t)m0 * CDIM + (size_t)l15 * CDIM + l4 * 8;

        f4 rawA[8], rawB[8];
        #pragma unroll
        for (int ks = 0; ks < 8; ks++) {
            rawA[ks] = *(const f4*)(fp + ks * 32);
            rawB[ks] = *(const f4*)(fp + ks * 32 + 4);
        }
        __builtin_amdgcn_sched_barrier(0);

        f4 acc[4];
        #pragma unroll
        for (int mi = 0; mi < 4; mi++) acc[mi] = (f4){0.f, 0.f, 0.f, 0.f};
        #pragma unroll
        for (int ks = 0; ks < 8; ks++) {
            const bf16x8 af = cvt8(rawA[ks], rawB[ks]);
            #pragma unroll
            for (int mi = 0; mi < 4; mi++) {
                const int r = mi * 16 + l15;
                const bf16x8 wfr = *(const bf16x8*)((const char*)Wlds + r * 512
                                      + ((ks * 64 + l4 * 16) ^ ((r & 7) << 4)));
                acc[mi] = __builtin_amdgcn_mfma_f32_16x16x32_bf16(wfr, af, acc[mi], 0, 0, 0);
            }
        }

        const int m = m0 + l15;
        #pragma unroll
        for (int mi = 0; mi < 4; mi++) {
            const int wr0 = wbase + mi * 16 + l4 * 4;
            *(ushort4*)(Qout + (size_t)m * CDIM + wr0) = packbf(acc[mi] + biasf[mi]);
        }
    }
}

// K+V projection: 16-wave blocks, dual 64 KB Wk/Wv slices. Two MFMA chains
// per feature burst (2x compute cover, kv_feat read 4x not 8x).
__global__ __launch_bounds__(1024, 4)
void proj_kv(const float* __restrict__ kvf,
             const float* __restrict__ Wk, const float* __restrict__ Wv,
             const float* __restrict__ bk, const float* __restrict__ bv,
             const float* __restrict__ sens, ushort* __restrict__ KVout,
             int M, int Npts, int nwg, int ngroups)
{
    __shared__ ushort Wlds[2][64 * CDIM];   // 64 KB

    const int orig = blockIdx.x;
    const int xcd = orig & 7, lin = orig >> 3;
    const int wgid = xcd * (nwg >> 3) + lin;
    const int chunk = wgid >> 2, ws = wgid & 3;

    const int tid  = threadIdx.x;
    const int lane = tid & 63;
    const int wid  = tid >> 6;
    const int l15  = lane & 15, l4 = lane >> 4;
    const int wbase = ws * 64;

    stage_w(Wk, wbase, &Wlds[0][0], tid);
    stage_w(Wv, wbase, &Wlds[1][0], tid);
    __syncthreads();

    f4 biasK[4], biasV[4];
    #pragma unroll
    for (int mi = 0; mi < 4; mi++) {
        biasK[mi] = *(const f4*)(bk + wbase + mi * 16 + l4 * 4);
        biasV[mi] = *(const f4*)(bv + wbase + mi * 16 + l4 * 4);
    }

    for (int g = chunk; g < ngroups; g += NCKV) {
        const int m0 = g * 256 + wid * 16;
        if (m0 >= M) continue;
        const float* fp = kvf + (size_t)m0 * CDIM + (size_t)l15 * CDIM + l4 * 8;

        f4 rawA[8], rawB[8];
        #pragma unroll
        for (int ks = 0; ks < 8; ks++) {
            rawA[ks] = *(const f4*)(fp + ks * 32);
            rawB[ks] = *(const f4*)(fp + ks * 32 + 4);
        }
        __builtin_amdgcn_sched_barrier(0);

        f4 accK[4], accV[4];
        #pragma unroll
        for (int mi = 0; mi < 4; mi++) {
            accK[mi] = (f4){0.f, 0.f, 0.f, 0.f};
            accV[mi] = (f4){0.f, 0.f, 0.f, 0.f};
        }
        #pragma unroll
        for (int ks = 0; ks < 8; ks++) {
            const bf16x8 af = cvt8(rawA[ks], rawB[ks]);
            #pragma unroll
            for (int mi = 0; mi < 4; mi++) {
                const int r = mi * 16 + l15;
                const int cb = (ks * 64 + l4 * 16) ^ ((r & 7) << 4);
                const bf16x8 wk = *(const bf16x8*)((const char*)&Wlds[0][0] + r * 512 + cb);
                accK[mi] = __builtin_amdgcn_mfma_f32_16x16x32_bf16(wk, af, accK[mi], 0, 0, 0);
                const bf16x8 wv = *(const bf16x8*)((const char*)&Wlds[1][0] + r * 512 + cb);
                accV[mi] = __builtin_amdgcn_mfma_f32_16x16x32_bf16(wv, af, accV[mi], 0, 0, 0);
            }
        }

        const int m = m0 + l15;
        const int nidx = m >= Npts ? m - Npts : m;
        const float sw = sens[nidx];
        #pragma unroll
        for (int mi = 0; mi < 4; mi++) {
            const int wr0 = wbase + mi * 16 + l4 * 4;
            f4 vk = (accK[mi] + biasK[mi]) * sw;
            f4 vv = (accV[mi] + biasV[mi]) * sw;
            *(ushort4*)(KVout + (size_t)m * 512 + wr0)       = packbf(vk);
            *(ushort4*)(KVout + (size_t)m * 512 + 256 + wr0) = packbf(vv);
        }
    }
}

// One wave per point (r8 gather shape). Batch-split dispatches keep the
// 51 MB per-batch KV gather set L3-resident.
__global__ __launch_bounds__(256, 4)
void attn_ln_bf(const ushort* __restrict__ Qb, float* __restrict__ Out,
                const ushort* __restrict__ KV, const int* __restrict__ knn,
                const float* __restrict__ ln_g, const float* __restrict__ ln_b,
                int Npts, int base)
{
    const int n = blockIdx.x * 4 + (threadIdx.x >> 6);
    if (n >= Npts) return;
    const int lane = threadIdx.x & 63;
    const size_t row = (size_t)(base + n);

    ushort4 qh = *(const ushort4*)(Qb + row * CDIM + lane * 4);
    f4 q;
    q[0] = bf2f(qh.x); q[1] = bf2f(qh.y); q[2] = bf2f(qh.z); q[3] = bf2f(qh.w);

    const int ns = __builtin_amdgcn_readfirstlane(n);
    const int* ki = knn + ns * KNN;
    int idxs[KNN];
    #pragma unroll
    for (int j = 0; j < KNN; j++) idxs[j] = ki[j];

    ushort4 kr[KNN], vr[KNN];
    #pragma unroll
    for (int j = 0; j < KNN; j++) {
        const ushort* rec = KV + (size_t)(base + idxs[j]) * 512;
        kr[j] = *(const ushort4*)(rec + lane * 4);
        vr[j] = *(const ushort4*)(rec + 256 + lane * 4);
    }

    float d[KNN];
    #pragma unroll
    for (int j = 0; j < KNN; j++)
        d[j] = q[0] * bf2f(kr[j].x) + q[1] * bf2f(kr[j].y)
             + q[2] * bf2f(kr[j].z) + q[3] * bf2f(kr[j].w);

    #pragma unroll
    for (int m = 1; m < 64; m <<= 1) {
        #pragma unroll
        for (int j = 0; j < KNN; j++) d[j] += __shfl_xor(d[j], m, 64);
    }

    float mx = -1e30f;
    #pragma unroll
    for (int j = 0; j < KNN; j++) { d[j] *= 0.0625f; mx = fmaxf(mx, d[j]); }
    float s = 0.f;
    #pragma unroll
    for (int j = 0; j < KNN; j++) { d[j] = __expf(d[j] - mx); s += d[j]; }
    const float inv = 1.f / s;

    f4 o = (f4){0.f, 0.f, 0.f, 0.f};
    #pragma unroll
    for (int j = 0; j < KNN; j++) {
        const float pj = d[j] * inv;
        o[0] += pj * bf2f(vr[j].x); o[1] += pj * bf2f(vr[j].y);
        o[2] += pj * bf2f(vr[j].z); o[3] += pj * bf2f(vr[j].w);
    }

    f4 x = o + q;

    float ssum = x[0] + x[1] + x[2] + x[3];
    #pragma unroll
    for (int m = 1; m < 64; m <<= 1) ssum += __shfl_xor(ssum, m, 64);
    const float mu = ssum * (1.f / 256.f);

    f4 e;
    e[0] = x[0] - mu; e[1] = x[1] - mu; e[2] = x[2] - mu; e[3] = x[3] - mu;
    float vsum = e[0] * e[0] + e[1] * e[1] + e[2] * e[2] + e[3] * e[3];
    #pragma unroll
    for (int m = 1; m < 64; m <<= 1) vsum += __shfl_xor(vsum, m, 64);
    const float rstd = rsqrtf(vsum * (1.f / 256.f) + 1e-5f);

    const f4 g  = *(const f4*)(ln_g + lane * 4);
    const f4 bb = *(const f4*)(ln_b + lane * 4);
    f4 outv;
    outv[0] = e[0] * rstd * g[0] + bb[0];
    outv[1] = e[1] * rstd * g[1] + bb[1];
    outv[2] = e[2] * rstd * g[2] + bb[2];
    outv[3] = e[3] * rstd * g[3] + bb[3];
    __builtin_nontemporal_store(outv, (f4*)(Out + row * CDIM + lane * 4));
}

extern "C" void kernel_launch(void* const* d_in, const int* in_sizes, int n_in,
                              void* d_out, int out_size, void* d_ws, size_t ws_size,
                              hipStream_t stream)
{
    const float* q_feat  = (const float*)d_in[0];
    const float* kv_feat = (const float*)d_in[1];
    const int*   knn     = (const int*)d_in[2];
    const float* sens    = (const float*)d_in[3];
    const float* Wq_w    = (const float*)d_in[4];
    const float* Wq_b    = (const float*)d_in[5];
    const float* Wk_w    = (const float*)d_in[6];
    const float* Wk_b    = (const float*)d_in[7];
    const float* Wv_w    = (const float*)d_in[8];
    const float* Wv_b    = (const float*)d_in[9];
    const float* ln_g    = (const float*)d_in[10];
    const float* ln_b    = (const float*)d_in[11];

    const int Npts = in_sizes[3];              // N = 50000
    const int M    = in_sizes[0] / CDIM;       // B*N = 100000
    const int ngroups = (M + 255) / 256;       // 391 groups of 256 rows

    ushort* Qb   = (ushort*)d_ws;              // [M][256] bf16   (51.2 MB)
    ushort* KVtb = Qb + (size_t)M * CDIM;      // [M] 1KB records (102.4 MB)

    proj_kv<<<4 * NCKV, 1024, 0, stream>>>(kv_feat, Wk_w, Wv_w, Wk_b, Wv_b,
                                           sens, KVtb, M, Npts, 4 * NCKV, ngroups);
    proj_q<<<4 * NCQ, 1024, 0, stream>>>(q_feat, Wq_w, Wq_b, Qb,
                                         M, 4 * NCQ, ngroups);

    const int nattn = (Npts + 3) / 4;
    attn_ln_bf<<<nattn, 256, 0, stream>>>(Qb, (float*)d_out, KVtb, knn,
                                          ln_g, ln_b, Npts, 0);
    attn_ln_bf<<<nattn, 256, 0, stream>>>(Qb, (float*)d_out, KVtb, knn,
                                          ln_g, ln_b, Npts, Npts);
}

// Round 13
// 391.080 us; speedup vs baseline: 2.0757x; 1.0039x over previous
//
#include <hip/hip_runtime.h>
#include <hip/hip_bf16.h>
#include <cstdint>

#define CDIM 256
#define KNN  16
#define NCQ  128    // Q chunks:  grid 4*128 = 512 blocks (2/CU, all resident)
#define NCKV 64     // KV chunks: grid 4*64  = 256 blocks (1/CU, all resident)

typedef __attribute__((ext_vector_type(8))) __bf16 bf16x8;
typedef __attribute__((ext_vector_type(4))) float  f4;

__device__ inline ushort f2bf(float f) {
    __bf16 b = (__bf16)f;
    return __builtin_bit_cast(ushort, b);
}
__device__ inline float bf2f(ushort h) {
    return __builtin_bit_cast(float, (unsigned int)h << 16);
}
__device__ inline bf16x8 cvt8(f4 a, f4 b) {
    bf16x8 r;
    r[0] = (__bf16)a[0]; r[1] = (__bf16)a[1]; r[2] = (__bf16)a[2]; r[3] = (__bf16)a[3];
    r[4] = (__bf16)b[0]; r[5] = (__bf16)b[1]; r[6] = (__bf16)b[2]; r[7] = (__bf16)b[3];
    return r;
}
__device__ inline ushort4 packbf(f4 v) {
    ushort4 h;
    h.x = f2bf(v[0]); h.y = f2bf(v[1]); h.z = f2bf(v[2]); h.w = f2bf(v[3]);
    return h;
}

// stage a 64-row x 256-col f32 weight slice -> bf16 LDS, XOR-swizzled.
__device__ inline void stage_w(const float* Wm, int wbase, ushort* dst, int tid) {
    #pragma unroll
    for (int i = 0; i < 4; i++) {
        int idx = i * 1024 + tid;
        int row = idx >> 6, c4 = idx & 63;
        float4 v = *(const float4*)(Wm + (size_t)(wbase + row) * CDIM + c4 * 4);
        ushort4 h;
        h.x = f2bf(v.x); h.y = f2bf(v.y); h.z = f2bf(v.z); h.w = f2bf(v.w);
        *(ushort4*)((char*)dst + row * 512 + ((c4 * 8) ^ ((row & 7) << 4))) = h;
    }
}

// Q projection: 16-wave blocks, one 32 KB Wq slice (r12-proven).
__global__ __launch_bounds__(1024, 4)
void proj_q(const float* __restrict__ qf, const float* __restrict__ Wq,
            const float* __restrict__ bq, ushort* __restrict__ Qout,
            int M, int nwg, int ngroups)
{
    __shared__ ushort Wlds[64 * CDIM];   // 32 KB

    const int orig = blockIdx.x;
    const int xcd = orig & 7, lin = orig >> 3;
    const int wgid = xcd * (nwg >> 3) + lin;       // nwg % 8 == 0
    const int chunk = wgid >> 2, ws = wgid & 3;

    const int tid  = threadIdx.x;
    const int lane = tid & 63;
    const int wid  = tid >> 6;                     // 0..15
    const int l15  = lane & 15, l4 = lane >> 4;
    const int wbase = ws * 64;

    stage_w(Wq, wbase, Wlds, tid);
    __syncthreads();

    f4 biasf[4];
    #pragma unroll
    for (int mi = 0; mi < 4; mi++)
        biasf[mi] = *(const f4*)(bq + wbase + mi * 16 + l4 * 4);

    for (int g = chunk; g < ngroups; g += NCQ) {
        const int m0 = g * 256 + wid * 16;
        if (m0 >= M) continue;                     // M % 16 == 0
        const float* fp = qf + (size_t)m0 * CDIM + (size_t)l15 * CDIM + l4 * 8;

        f4 rawA[8], rawB[8];
        #pragma unroll
        for (int ks = 0; ks < 8; ks++) {
            rawA[ks] = *(const f4*)(fp + ks * 32);
            rawB[ks] = *(const f4*)(fp + ks * 32 + 4);
        }
        __builtin_amdgcn_sched_barrier(0);

        f4 acc[4];
        #pragma unroll
        for (int mi = 0; mi < 4; mi++) acc[mi] = (f4){0.f, 0.f, 0.f, 0.f};
        #pragma unroll
        for (int ks = 0; ks < 8; ks++) {
            const bf16x8 af = cvt8(rawA[ks], rawB[ks]);
            #pragma unroll
            for (int mi = 0; mi < 4; mi++) {
                const int r = mi * 16 + l15;
                const bf16x8 wfr = *(const bf16x8*)((const char*)Wlds + r * 512
                                      + ((ks * 64 + l4 * 16) ^ ((r & 7) << 4)));
                acc[mi] = __builtin_amdgcn_mfma_f32_16x16x32_bf16(wfr, af, acc[mi], 0, 0, 0);
            }
        }

        const int m = m0 + l15;
        #pragma unroll
        for (int mi = 0; mi < 4; mi++) {
            const int wr0 = wbase + mi * 16 + l4 * 4;
            *(ushort4*)(Qout + (size_t)m * CDIM + wr0) = packbf(acc[mi] + biasf[mi]);
        }
    }
}

// K+V projection: 16-wave blocks, dual 64 KB Wk/Wv slices (r12-proven).
__global__ __launch_bounds__(1024, 4)
void proj_kv(const float* __restrict__ kvf,
             const float* __restrict__ Wk, const float* __restrict__ Wv,
             const float* __restrict__ bk, const float* __restrict__ bv,
             const float* __restrict__ sens, ushort* __restrict__ KVout,
             int M, int Npts, int nwg, int ngroups)
{
    __shared__ ushort Wlds[2][64 * CDIM];   // 64 KB

    const int orig = blockIdx.x;
    const int xcd = orig & 7, lin = orig >> 3;
    const int wgid = xcd * (nwg >> 3) + lin;
    const int chunk = wgid >> 2, ws = wgid & 3;

    const int tid  = threadIdx.x;
    const int lane = tid & 63;
    const int wid  = tid >> 6;
    const int l15  = lane & 15, l4 = lane >> 4;
    const int wbase = ws * 64;

    stage_w(Wk, wbase, &Wlds[0][0], tid);
    stage_w(Wv, wbase, &Wlds[1][0], tid);
    __syncthreads();

    f4 biasK[4], biasV[4];
    #pragma unroll
    for (int mi = 0; mi < 4; mi++) {
        biasK[mi] = *(const f4*)(bk + wbase + mi * 16 + l4 * 4);
        biasV[mi] = *(const f4*)(bv + wbase + mi * 16 + l4 * 4);
    }

    for (int g = chunk; g < ngroups; g += NCKV) {
        const int m0 = g * 256 + wid * 16;
        if (m0 >= M) continue;
        const float* fp = kvf + (size_t)m0 * CDIM + (size_t)l15 * CDIM + l4 * 8;

        f4 rawA[8], rawB[8];
        #pragma unroll
        for (int ks = 0; ks < 8; ks++) {
            rawA[ks] = *(const f4*)(fp + ks * 32);
            rawB[ks] = *(const f4*)(fp + ks * 32 + 4);
        }
        __builtin_amdgcn_sched_barrier(0);

        f4 accK[4], accV[4];
        #pragma unroll
        for (int mi = 0; mi < 4; mi++) {
            accK[mi] = (f4){0.f, 0.f, 0.f, 0.f};
            accV[mi] = (f4){0.f, 0.f, 0.f, 0.f};
        }
        #pragma unroll
        for (int ks = 0; ks < 8; ks++) {
            const bf16x8 af = cvt8(rawA[ks], rawB[ks]);
            #pragma unroll
            for (int mi = 0; mi < 4; mi++) {
                const int r = mi * 16 + l15;
                const int cb = (ks * 64 + l4 * 16) ^ ((r & 7) << 4);
                const bf16x8 wk = *(const bf16x8*)((const char*)&Wlds[0][0] + r * 512 + cb);
                accK[mi] = __builtin_amdgcn_mfma_f32_16x16x32_bf16(wk, af, accK[mi], 0, 0, 0);
                const bf16x8 wv = *(const bf16x8*)((const char*)&Wlds[1][0] + r * 512 + cb);
                accV[mi] = __builtin_amdgcn_mfma_f32_16x16x32_bf16(wv, af, accV[mi], 0, 0, 0);
            }
        }

        const int m = m0 + l15;
        const int nidx = m >= Npts ? m - Npts : m;
        const float sw = sens[nidx];
        #pragma unroll
        for (int mi = 0; mi < 4; mi++) {
            const int wr0 = wbase + mi * 16 + l4 * 4;
            f4 vk = (accK[mi] + biasK[mi]) * sw;
            f4 vv = (accV[mi] + biasV[mi]) * sw;
            *(ushort4*)(KVout + (size_t)m * 512 + wr0)       = packbf(vk);
            *(ushort4*)(KVout + (size_t)m * 512 + 256 + wr0) = packbf(vv);
        }
    }
}

// One wave per point. Round 13: ALL 32 gathers batched into registers and
// pinned by sched_barrier(0) -- same cure as proj r5/r6 (VGPR 28 showed the
// compiler had serialized the gathers -> latency-bound at 47% HBM).
// Single dispatch covers both batches (Npts % 4 == 0: no straddling block).
__global__ __launch_bounds__(256, 4)
void attn_ln_bf(const ushort* __restrict__ Qb, float* __restrict__ Out,
                const ushort* __restrict__ KV, const int* __restrict__ knn,
                const float* __restrict__ ln_g, const float* __restrict__ ln_b,
                int Npts)
{
    const int gi = blockIdx.x * 4 + (threadIdx.x >> 6);   // [0, 2*Npts)
    const int lane = threadIdx.x & 63;
    const int base = gi >= Npts ? Npts : 0;
    const int n    = gi - base;
    if (n >= Npts) return;

    const ushort4 qh = *(const ushort4*)(Qb + (size_t)gi * CDIM + lane * 4);

    const int ns = __builtin_amdgcn_readfirstlane(n);
    const int* ki = knn + ns * KNN;
    int idxs[KNN];
    #pragma unroll
    for (int j = 0; j < KNN; j++) idxs[j] = ki[j];

    // batched gathers: all 32 in flight before any use
    ushort4 kr[KNN], vr[KNN];
    #pragma unroll
    for (int j = 0; j < KNN; j++) {
        const ushort* rec = KV + (size_t)(base + idxs[j]) * 512;
        kr[j] = *(const ushort4*)(rec + lane * 4);
        vr[j] = *(const ushort4*)(rec + 256 + lane * 4);
    }
    __builtin_amdgcn_sched_barrier(0);

    f4 q;
    q[0] = bf2f(qh.x); q[1] = bf2f(qh.y); q[2] = bf2f(qh.z); q[3] = bf2f(qh.w);

    float d[KNN];
    #pragma unroll
    for (int j = 0; j < KNN; j++)
        d[j] = q[0] * bf2f(kr[j].x) + q[1] * bf2f(kr[j].y)
             + q[2] * bf2f(kr[j].z) + q[3] * bf2f(kr[j].w);

    #pragma unroll
    for (int m = 1; m < 64; m <<= 1) {
        #pragma unroll
        for (int j = 0; j < KNN; j++) d[j] += __shfl_xor(d[j], m, 64);
    }

    float mx = -1e30f;
    #pragma unroll
    for (int j = 0; j < KNN; j++) { d[j] *= 0.0625f; mx = fmaxf(mx, d[j]); }
    float s = 0.f;
    #pragma unroll
    for (int j = 0; j < KNN; j++) { d[j] = __expf(d[j] - mx); s += d[j]; }
    const float inv = 1.f / s;

    f4 o = (f4){0.f, 0.f, 0.f, 0.f};
    #pragma unroll
    for (int j = 0; j < KNN; j++) {
        const float pj = d[j] * inv;
        o[0] += pj * bf2f(vr[j].x); o[1] += pj * bf2f(vr[j].y);
        o[2] += pj * bf2f(vr[j].z); o[3] += pj * bf2f(vr[j].w);
    }

    f4 x = o + q;

    float ssum = x[0] + x[1] + x[2] + x[3];
    #pragma unroll
    for (int m = 1; m < 64; m <<= 1) ssum += __shfl_xor(ssum, m, 64);
    const float mu = ssum * (1.f / 256.f);

    f4 e;
    e[0] = x[0] - mu; e[1] = x[1] - mu; e[2] = x[2] - mu; e[3] = x[3] - mu;
    float vsum = e[0] * e[0] + e[1] * e[1] + e[2] * e[2] + e[3] * e[3];
    #pragma unroll
    for (int m = 1; m < 64; m <<= 1) vsum += __shfl_xor(vsum, m, 64);
    const float rstd = rsqrtf(vsum * (1.f / 256.f) + 1e-5f);

    const f4 g  = *(const f4*)(ln_g + lane * 4);
    const f4 bb = *(const f4*)(ln_b + lane * 4);
    f4 outv;
    outv[0] = e[0] * rstd * g[0] + bb[0];
    outv[1] = e[1] * rstd * g[1] + bb[1];
    outv[2] = e[2] * rstd * g[2] + bb[2];
    outv[3] = e[3] * rstd * g[3] + bb[3];
    __builtin_nontemporal_store(outv, (f4*)(Out + (size_t)gi * CDIM + lane * 4));
}

extern "C" void kernel_launch(void* const* d_in, const int* in_sizes, int n_in,
                              void* d_out, int out_size, void* d_ws, size_t ws_size,
                              hipStream_t stream)
{
    const float* q_feat  = (const float*)d_in[0];
    const float* kv_feat = (const float*)d_in[1];
    const int*   knn     = (const int*)d_in[2];
    const float* sens    = (const float*)d_in[3];
    const float* Wq_w    = (const float*)d_in[4];
    const float* Wq_b    = (const float*)d_in[5];
    const float* Wk_w    = (const float*)d_in[6];
    const float* Wk_b    = (const float*)d_in[7];
    const float* Wv_w    = (const float*)d_in[8];
    const float* Wv_b    = (const float*)d_in[9];
    const float* ln_g    = (const float*)d_in[10];
    const float* ln_b    = (const float*)d_in[11];

    const int Npts = in_sizes[3];              // N = 50000
    const int M    = in_sizes[0] / CDIM;       // B*N = 100000
    const int ngroups = (M + 255) / 256;       // 391 groups of 256 rows

    ushort* Qb   = (ushort*)d_ws;              // [M][256] bf16   (51.2 MB)
    ushort* KVtb = Qb + (size_t)M * CDIM;      // [M] 1KB records (102.4 MB)

    proj_kv<<<4 * NCKV, 1024, 0, stream>>>(kv_feat, Wk_w, Wv_w, Wk_b, Wv_b,
                                           sens, KVtb, M, Npts, 4 * NCKV, ngroups);
    proj_q<<<4 * NCQ, 1024, 0, stream>>>(q_feat, Wq_w, Wq_b, Qb,
                                         M, 4 * NCQ, ngroups);

    attn_ln_bf<<<(2 * Npts + 3) / 4, 256, 0, stream>>>(Qb, (float*)d_out, KVtb,
                                                       knn, ln_g, ln_b, Npts);
}

// Round 14
// 390.538 us; speedup vs baseline: 2.0785x; 1.0014x over previous
//
#include <hip/hip_runtime.h>
#include <hip/hip_bf16.h>
#include <cstdint>

#define CDIM 256
#define KNN  16
#define NCQ  128    // Q chunks:  grid 4*128 = 512 blocks (2/CU, all resident)
#define NCKV 64     // KV chunks: grid 4*64  = 256 blocks (1/CU, all resident)

typedef __attribute__((ext_vector_type(8))) __bf16 bf16x8;
typedef __attribute__((ext_vector_type(4))) float  f4;

__device__ inline ushort f2bf(float f) {
    __bf16 b = (__bf16)f;
    return __builtin_bit_cast(ushort, b);
}
__device__ inline float bf2f(ushort h) {
    return __builtin_bit_cast(float, (unsigned int)h << 16);
}
__device__ inline bf16x8 cvt8(f4 a, f4 b) {
    bf16x8 r;
    r[0] = (__bf16)a[0]; r[1] = (__bf16)a[1]; r[2] = (__bf16)a[2]; r[3] = (__bf16)a[3];
    r[4] = (__bf16)b[0]; r[5] = (__bf16)b[1]; r[6] = (__bf16)b[2]; r[7] = (__bf16)b[3];
    return r;
}
__device__ inline ushort4 packbf(f4 v) {
    ushort4 h;
    h.x = f2bf(v[0]); h.y = f2bf(v[1]); h.z = f2bf(v[2]); h.w = f2bf(v[3]);
    return h;
}

// stage a 64-row x 256-col f32 weight slice -> bf16 LDS, XOR-swizzled.
__device__ inline void stage_w(const float* Wm, int wbase, ushort* dst, int tid) {
    #pragma unroll
    for (int i = 0; i < 4; i++) {
        int idx = i * 1024 + tid;
        int row = idx >> 6, c4 = idx & 63;
        float4 v = *(const float4*)(Wm + (size_t)(wbase + row) * CDIM + c4 * 4);
        ushort4 h;
        h.x = f2bf(v.x); h.y = f2bf(v.y); h.z = f2bf(v.z); h.w = f2bf(v.w);
        *(ushort4*)((char*)dst + row * 512 + ((c4 * 8) ^ ((row & 7) << 4))) = h;
    }
}

// Q projection: 16-wave blocks, one 32 KB Wq slice (r12-proven).
__global__ __launch_bounds__(1024, 4)
void proj_q(const float* __restrict__ qf, const float* __restrict__ Wq,
            const float* __restrict__ bq, ushort* __restrict__ Qout,
            int M, int nwg, int ngroups)
{
    __shared__ ushort Wlds[64 * CDIM];   // 32 KB

    const int orig = blockIdx.x;
    const int xcd = orig & 7, lin = orig >> 3;
    const int wgid = xcd * (nwg >> 3) + lin;       // nwg % 8 == 0
    const int chunk = wgid >> 2, ws = wgid & 3;

    const int tid  = threadIdx.x;
    const int lane = tid & 63;
    const int wid  = tid >> 6;                     // 0..15
    const int l15  = lane & 15, l4 = lane >> 4;
    const int wbase = ws * 64;

    stage_w(Wq, wbase, Wlds, tid);
    __syncthreads();

    f4 biasf[4];
    #pragma unroll
    for (int mi = 0; mi < 4; mi++)
        biasf[mi] = *(const f4*)(bq + wbase + mi * 16 + l4 * 4);

    for (int g = chunk; g < ngroups; g += NCQ) {
        const int m0 = g * 256 + wid * 16;
        if (m0 >= M) continue;                     // M % 16 == 0
        const float* fp = qf + (size_t)m0 * CDIM + (size_t)l15 * CDIM + l4 * 8;

        f4 rawA[8], rawB[8];
        #pragma unroll
        for (int ks = 0; ks < 8; ks++) {
            rawA[ks] = *(const f4*)(fp + ks * 32);
            rawB[ks] = *(const f4*)(fp + ks * 32 + 4);
        }
        __builtin_amdgcn_sched_barrier(0);

        f4 acc[4];
        #pragma unroll
        for (int mi = 0; mi < 4; mi++) acc[mi] = (f4){0.f, 0.f, 0.f, 0.f};
        #pragma unroll
        for (int ks = 0; ks < 8; ks++) {
            const bf16x8 af = cvt8(rawA[ks], rawB[ks]);
            #pragma unroll
            for (int mi = 0; mi < 4; mi++) {
                const int r = mi * 16 + l15;
                const bf16x8 wfr = *(const bf16x8*)((const char*)Wlds + r * 512
                                      + ((ks * 64 + l4 * 16) ^ ((r & 7) << 4)));
                acc[mi] = __builtin_amdgcn_mfma_f32_16x16x32_bf16(wfr, af, acc[mi], 0, 0, 0);
            }
        }

        const int m = m0 + l15;
        #pragma unroll
        for (int mi = 0; mi < 4; mi++) {
            const int wr0 = wbase + mi * 16 + l4 * 4;
            *(ushort4*)(Qout + (size_t)m * CDIM + wr0) = packbf(acc[mi] + biasf[mi]);
        }
    }
}

// K+V projection: 16-wave blocks, dual 64 KB Wk/Wv slices (r12-proven).
// Writes SEPARATE Kt / Vt arrays (phase-split attn gathers them separately).
__global__ __launch_bounds__(1024, 4)
void proj_kv(const float* __restrict__ kvf,
             const float* __restrict__ Wk, const float* __restrict__ Wv,
             const float* __restrict__ bk, const float* __restrict__ bv,
             const float* __restrict__ sens,
             ushort* __restrict__ Kt, ushort* __restrict__ Vt,
             int M, int Npts, int nwg, int ngroups)
{
    __shared__ ushort Wlds[2][64 * CDIM];   // 64 KB

    const int orig = blockIdx.x;
    const int xcd = orig & 7, lin = orig >> 3;
    const int wgid = xcd * (nwg >> 3) + lin;
    const int chunk = wgid >> 2, ws = wgid & 3;

    const int tid  = threadIdx.x;
    const int lane = tid & 63;
    const int wid  = tid >> 6;
    const int l15  = lane & 15, l4 = lane >> 4;
    const int wbase = ws * 64;

    stage_w(Wk, wbase, &Wlds[0][0], tid);
    stage_w(Wv, wbase, &Wlds[1][0], tid);
    __syncthreads();

    f4 biasK[4], biasV[4];
    #pragma unroll
    for (int mi = 0; mi < 4; mi++) {
        biasK[mi] = *(const f4*)(bk + wbase + mi * 16 + l4 * 4);
        biasV[mi] = *(const f4*)(bv + wbase + mi * 16 + l4 * 4);
    }

    for (int g = chunk; g < ngroups; g += NCKV) {
        const int m0 = g * 256 + wid * 16;
        if (m0 >= M) continue;
        const float* fp = kvf + (size_t)m0 * CDIM + (size_t)l15 * CDIM + l4 * 8;

        f4 rawA[8], rawB[8];
        #pragma unroll
        for (int ks = 0; ks < 8; ks++) {
            rawA[ks] = *(const f4*)(fp + ks * 32);
            rawB[ks] = *(const f4*)(fp + ks * 32 + 4);
        }
        __builtin_amdgcn_sched_barrier(0);

        f4 accK[4], accV[4];
        #pragma unroll
        for (int mi = 0; mi < 4; mi++) {
            accK[mi] = (f4){0.f, 0.f, 0.f, 0.f};
            accV[mi] = (f4){0.f, 0.f, 0.f, 0.f};
        }
        #pragma unroll
        for (int ks = 0; ks < 8; ks++) {
            const bf16x8 af = cvt8(rawA[ks], rawB[ks]);
            #pragma unroll
            for (int mi = 0; mi < 4; mi++) {
                const int r = mi * 16 + l15;
                const int cb = (ks * 64 + l4 * 16) ^ ((r & 7) << 4);
                const bf16x8 wk = *(const bf16x8*)((const char*)&Wlds[0][0] + r * 512 + cb);
                accK[mi] = __builtin_amdgcn_mfma_f32_16x16x32_bf16(wk, af, accK[mi], 0, 0, 0);
                const bf16x8 wv = *(const bf16x8*)((const char*)&Wlds[1][0] + r * 512 + cb);
                accV[mi] = __builtin_amdgcn_mfma_f32_16x16x32_bf16(wv, af, accV[mi], 0, 0, 0);
            }
        }

        const int m = m0 + l15;
        const int nidx = m >= Npts ? m - Npts : m;
        const float sw = sens[nidx];
        #pragma unroll
        for (int mi = 0; mi < 4; mi++) {
            const int wr0 = wbase + mi * 16 + l4 * 4;
            *(ushort4*)(Kt + (size_t)m * CDIM + wr0) = packbf((accK[mi] + biasK[mi]) * sw);
            *(ushort4*)(Vt + (size_t)m * CDIM + wr0) = packbf((accV[mi] + biasV[mi]) * sw);
        }
    }
}

// Phase A: per point gather 16 K rows, dot, softmax -> 16 probs. The only
// random-gather set live in this dispatch is Kt (51 MB) -> L3-retainable.
__global__ __launch_bounds__(256, 4)
void attn_score(const ushort* __restrict__ Qb, const ushort* __restrict__ Kt,
                const int* __restrict__ knn, float* __restrict__ probs, int Npts)
{
    const int gi = blockIdx.x * 4 + (threadIdx.x >> 6);   // [0, 2*Npts)
    const int lane = threadIdx.x & 63;
    const int base = gi >= Npts ? Npts : 0;
    const int n    = gi - base;
    if (n >= Npts) return;

    const ushort4 qh = *(const ushort4*)(Qb + (size_t)gi * CDIM + lane * 4);

    const int ns = __builtin_amdgcn_readfirstlane(n);
    const int* ki = knn + ns * KNN;
    int idxs[KNN];
    #pragma unroll
    for (int j = 0; j < KNN; j++) idxs[j] = ki[j];

    ushort4 kr[KNN];
    #pragma unroll
    for (int j = 0; j < KNN; j++)
        kr[j] = *(const ushort4*)(Kt + (size_t)(base + idxs[j]) * CDIM + lane * 4);
    __builtin_amdgcn_sched_barrier(0);

    f4 q;
    q[0] = bf2f(qh.x); q[1] = bf2f(qh.y); q[2] = bf2f(qh.z); q[3] = bf2f(qh.w);

    float d[KNN];
    #pragma unroll
    for (int j = 0; j < KNN; j++)
        d[j] = q[0] * bf2f(kr[j].x) + q[1] * bf2f(kr[j].y)
             + q[2] * bf2f(kr[j].z) + q[3] * bf2f(kr[j].w);

    #pragma unroll
    for (int m = 1; m < 64; m <<= 1) {
        #pragma unroll
        for (int j = 0; j < KNN; j++) d[j] += __shfl_xor(d[j], m, 64);
    }

    float mx = -1e30f;
    #pragma unroll
    for (int j = 0; j < KNN; j++) { d[j] *= 0.0625f; mx = fmaxf(mx, d[j]); }
    float s = 0.f;
    #pragma unroll
    for (int j = 0; j < KNN; j++) { d[j] = __expf(d[j] - mx); s += d[j]; }
    const float inv = 1.f / s;

    if (lane == 0) {
        float* pp = probs + (size_t)gi * KNN;
        *(f4*)(pp)      = (f4){d[0] * inv,  d[1] * inv,  d[2] * inv,  d[3] * inv};
        *(f4*)(pp + 4)  = (f4){d[4] * inv,  d[5] * inv,  d[6] * inv,  d[7] * inv};
        *(f4*)(pp + 8)  = (f4){d[8] * inv,  d[9] * inv,  d[10] * inv, d[11] * inv};
        *(f4*)(pp + 12) = (f4){d[12] * inv, d[13] * inv, d[14] * inv, d[15] * inv};
    }
}

// Phase B: per point gather 16 V rows, weighted sum, residual + LayerNorm.
// Random-gather set: Vt only (51 MB).
__global__ __launch_bounds__(256, 4)
void attn_pv(const ushort* __restrict__ Qb, const ushort* __restrict__ Vt,
             const int* __restrict__ knn, const float* __restrict__ probs,
             float* __restrict__ Out,
             const float* __restrict__ ln_g, const float* __restrict__ ln_b,
             int Npts)
{
    const int gi = blockIdx.x * 4 + (threadIdx.x >> 6);
    const int lane = threadIdx.x & 63;
    const int base = gi >= Npts ? Npts : 0;
    const int n    = gi - base;
    if (n >= Npts) return;

    const int ns = __builtin_amdgcn_readfirstlane(n);
    const int gs = __builtin_amdgcn_readfirstlane(gi);
    const int* ki = knn + ns * KNN;
    int idxs[KNN];
    #pragma unroll
    for (int j = 0; j < KNN; j++) idxs[j] = ki[j];

    ushort4 vr[KNN];
    #pragma unroll
    for (int j = 0; j < KNN; j++)
        vr[j] = *(const ushort4*)(Vt + (size_t)(base + idxs[j]) * CDIM + lane * 4);
    __builtin_amdgcn_sched_barrier(0);

    // wave-uniform prob reads -> scalar loads
    const float* pp = probs + (size_t)gs * KNN;
    float p[KNN];
    #pragma unroll
    for (int j = 0; j < KNN; j++) p[j] = pp[j];

    const ushort4 qh = *(const ushort4*)(Qb + (size_t)gi * CDIM + lane * 4);
    f4 q;
    q[0] = bf2f(qh.x); q[1] = bf2f(qh.y); q[2] = bf2f(qh.z); q[3] = bf2f(qh.w);

    f4 o = (f4){0.f, 0.f, 0.f, 0.f};
    #pragma unroll
    for (int j = 0; j < KNN; j++) {
        o[0] += p[j] * bf2f(vr[j].x); o[1] += p[j] * bf2f(vr[j].y);
        o[2] += p[j] * bf2f(vr[j].z); o[3] += p[j] * bf2f(vr[j].w);
    }

    f4 x = o + q;

    float ssum = x[0] + x[1] + x[2] + x[3];
    #pragma unroll
    for (int m = 1; m < 64; m <<= 1) ssum += __shfl_xor(ssum, m, 64);
    const float mu = ssum * (1.f / 256.f);

    f4 e;
    e[0] = x[0] - mu; e[1] = x[1] - mu; e[2] = x[2] - mu; e[3] = x[3] - mu;
    float vsum = e[0] * e[0] + e[1] * e[1] + e[2] * e[2] + e[3] * e[3];
    #pragma unroll
    for (int m = 1; m < 64; m <<= 1) vsum += __shfl_xor(vsum, m, 64);
    const float rstd = rsqrtf(vsum * (1.f / 256.f) + 1e-5f);

    const f4 g  = *(const f4*)(ln_g + lane * 4);
    const f4 bb = *(const f4*)(ln_b + lane * 4);
    f4 outv;
    outv[0] = e[0] * rstd * g[0] + bb[0];
    outv[1] = e[1] * rstd * g[1] + bb[1];
    outv[2] = e[2] * rstd * g[2] + bb[2];
    outv[3] = e[3] * rstd * g[3] + bb[3];
    __builtin_nontemporal_store(outv, (f4*)(Out + (size_t)gi * CDIM + lane * 4));
}

extern "C" void kernel_launch(void* const* d_in, const int* in_sizes, int n_in,
                              void* d_out, int out_size, void* d_ws, size_t ws_size,
                              hipStream_t stream)
{
    const float* q_feat  = (const float*)d_in[0];
    const float* kv_feat = (const float*)d_in[1];
    const int*   knn     = (const int*)d_in[2];
    const float* sens    = (const float*)d_in[3];
    const float* Wq_w    = (const float*)d_in[4];
    const float* Wq_b    = (const float*)d_in[5];
    const float* Wk_w    = (const float*)d_in[6];
    const float* Wk_b    = (const float*)d_in[7];
    const float* Wv_w    = (const float*)d_in[8];
    const float* Wv_b    = (const float*)d_in[9];
    const float* ln_g    = (const float*)d_in[10];
    const float* ln_b    = (const float*)d_in[11];

    const int Npts = in_sizes[3];              // N = 50000
    const int M    = in_sizes[0] / CDIM;       // B*N = 100000
    const int ngroups = (M + 255) / 256;       // 391 groups of 256 rows

    ushort* Qb  = (ushort*)d_ws;               // [M][256] bf16 (51.2 MB)
    ushort* Kt  = Qb + (size_t)M * CDIM;       // [M][256] bf16 (51.2 MB)
    ushort* Vt  = Kt + (size_t)M * CDIM;       // [M][256] bf16 (51.2 MB)
    float* probs = (float*)(Vt + (size_t)M * CDIM);  // [M][16] f32 (6.4 MB)

    proj_kv<<<4 * NCKV, 1024, 0, stream>>>(kv_feat, Wk_w, Wv_w, Wk_b, Wv_b,
                                           sens, Kt, Vt, M, Npts, 4 * NCKV, ngroups);
    proj_q<<<4 * NCQ, 1024, 0, stream>>>(q_feat, Wq_w, Wq_b, Qb,
                                         M, 4 * NCQ, ngroups);

    const int nblk = (2 * Npts + 3) / 4;
    attn_score<<<nblk, 256, 0, stream>>>(Qb, Kt, knn, probs, Npts);
    attn_pv<<<nblk, 256, 0, stream>>>(Qb, Vt, knn, probs, (float*)d_out,
                                      ln_g, ln_b, Npts);
}

// Round 15
// 381.741 us; speedup vs baseline: 2.1264x; 1.0230x over previous
//
#include <hip/hip_runtime.h>
#include <hip/hip_bf16.h>
#include <cstdint>

#define CDIM 256
#define KNN  16
#define NCH  64     // chunks; grid = 4 slices * 64 = 256 blocks, 1/CU, uniform

typedef __attribute__((ext_vector_type(8))) __bf16 bf16x8;
typedef __attribute__((ext_vector_type(4))) float  f4;
typedef __attribute__((ext_vector_type(4))) unsigned short u16x4;

__device__ inline ushort f2bf(float f) {
    __bf16 b = (__bf16)f;
    return __builtin_bit_cast(ushort, b);
}
__device__ inline float bf2f(ushort h) {
    return __builtin_bit_cast(float, (unsigned int)h << 16);
}
__device__ inline bf16x8 cvt8(f4 a, f4 b) {
    bf16x8 r;
    r[0] = (__bf16)a[0]; r[1] = (__bf16)a[1]; r[2] = (__bf16)a[2]; r[3] = (__bf16)a[3];
    r[4] = (__bf16)b[0]; r[5] = (__bf16)b[1]; r[6] = (__bf16)b[2]; r[7] = (__bf16)b[3];
    return r;
}
__device__ inline ushort4 packbf(f4 v) {
    ushort4 h;
    h.x = f2bf(v[0]); h.y = f2bf(v[1]); h.z = f2bf(v[2]); h.w = f2bf(v[3]);
    return h;
}

// stage a 64-row x 256-col f32 weight slice -> bf16 LDS, XOR-swizzled.
__device__ inline void stage_w(const float* Wm, int wbase, ushort* dst, int tid) {
    #pragma unroll
    for (int i = 0; i < 4; i++) {
        int idx = i * 1024 + tid;
        int row = idx >> 6, c4 = idx & 63;
        float4 v = *(const float4*)(Wm + (size_t)(wbase + row) * CDIM + c4 * 4);
        ushort4 h;
        h.x = f2bf(v.x); h.y = f2bf(v.y); h.z = f2bf(v.z); h.w = f2bf(v.w);
        *(ushort4*)((char*)dst + row * 512 + ((c4 * 8) ^ ((row & 7) << 4))) = h;
    }
}

// Unified QKV projection: every block stages Wq/Wk/Wv col-slices (96 KB LDS,
// 1 block/CU, 16 waves = 4/SIMD), then per 16-row group runs phase Q
// (qf burst -> 32 MFMA -> store) and phase KV (kvf burst -> dual-chain
// 64 MFMA -> store), reusing the raw-load registers (peak ~116 VGPR).
// One dispatch replaces proj_q + proj_kv: no boundary tail, zero imbalance.
__global__ __launch_bounds__(1024, 4)
void uni_proj(const float* __restrict__ qf, const float* __restrict__ kvf,
              const float* __restrict__ Wq, const float* __restrict__ Wk,
              const float* __restrict__ Wv,
              const float* __restrict__ bq, const float* __restrict__ bk,
              const float* __restrict__ bv, const float* __restrict__ sens,
              ushort* __restrict__ Qout, ushort* __restrict__ Kt,
              ushort* __restrict__ Vt, int M, int Npts, int nwg, int ngroups)
{
    __shared__ ushort Wlds[3][64 * CDIM];   // 96 KB

    const int orig = blockIdx.x;
    const int xcd = orig & 7, lin = orig >> 3;
    const int wgid = xcd * (nwg >> 3) + lin;       // nwg % 8 == 0
    const int chunk = wgid >> 2, ws = wgid & 3;    // 4 slices/chunk -> same XCD

    const int tid  = threadIdx.x;
    const int lane = tid & 63;
    const int wid  = tid >> 6;                     // 0..15
    const int l15  = lane & 15, l4 = lane >> 4;
    const int wbase = ws * 64;

    stage_w(Wq, wbase, &Wlds[0][0], tid);
    stage_w(Wk, wbase, &Wlds[1][0], tid);
    stage_w(Wv, wbase, &Wlds[2][0], tid);
    __syncthreads();

    for (int g = chunk; g < ngroups; g += NCH) {
        const int m0 = g * 256 + wid * 16;
        if (m0 >= M) continue;                     // M % 16 == 0
        const size_t fofs = (size_t)m0 * CDIM + (size_t)l15 * CDIM + l4 * 8;
        const int m = m0 + l15;

        // ---- phase Q ----
        {
            const float* fp = qf + fofs;
            f4 rawA[8], rawB[8];
            #pragma unroll
            for (int ks = 0; ks < 8; ks++) {
                rawA[ks] = *(const f4*)(fp + ks * 32);
                rawB[ks] = *(const f4*)(fp + ks * 32 + 4);
            }
            __builtin_amdgcn_sched_barrier(0);

            f4 acc[4];
            #pragma unroll
            for (int mi = 0; mi < 4; mi++) acc[mi] = (f4){0.f, 0.f, 0.f, 0.f};
            #pragma unroll
            for (int ks = 0; ks < 8; ks++) {
                const bf16x8 af = cvt8(rawA[ks], rawB[ks]);
                #pragma unroll
                for (int mi = 0; mi < 4; mi++) {
                    const int r = mi * 16 + l15;
                    const bf16x8 wfr = *(const bf16x8*)((const char*)&Wlds[0][0] + r * 512
                                          + ((ks * 64 + l4 * 16) ^ ((r & 7) << 4)));
                    acc[mi] = __builtin_amdgcn_mfma_f32_16x16x32_bf16(wfr, af, acc[mi], 0, 0, 0);
                }
            }
            #pragma unroll
            for (int mi = 0; mi < 4; mi++) {
                const int wr0 = wbase + mi * 16 + l4 * 4;
                const f4 bias = *(const f4*)(bq + wr0);
                *(ushort4*)(Qout + (size_t)m * CDIM + wr0) = packbf(acc[mi] + bias);
            }
        }

        // ---- phase KV (reuses raw registers) ----
        {
            const float* fp = kvf + fofs;
            f4 rawA[8], rawB[8];
            #pragma unroll
            for (int ks = 0; ks < 8; ks++) {
                rawA[ks] = *(const f4*)(fp + ks * 32);
                rawB[ks] = *(const f4*)(fp + ks * 32 + 4);
            }
            __builtin_amdgcn_sched_barrier(0);

            f4 accK[4], accV[4];
            #pragma unroll
            for (int mi = 0; mi < 4; mi++) {
                accK[mi] = (f4){0.f, 0.f, 0.f, 0.f};
                accV[mi] = (f4){0.f, 0.f, 0.f, 0.f};
            }
            #pragma unroll
            for (int ks = 0; ks < 8; ks++) {
                const bf16x8 af = cvt8(rawA[ks], rawB[ks]);
                #pragma unroll
                for (int mi = 0; mi < 4; mi++) {
                    const int r = mi * 16 + l15;
                    const int cb = (ks * 64 + l4 * 16) ^ ((r & 7) << 4);
                    const bf16x8 wk = *(const bf16x8*)((const char*)&Wlds[1][0] + r * 512 + cb);
                    accK[mi] = __builtin_amdgcn_mfma_f32_16x16x32_bf16(wk, af, accK[mi], 0, 0, 0);
                    const bf16x8 wv = *(const bf16x8*)((const char*)&Wlds[2][0] + r * 512 + cb);
                    accV[mi] = __builtin_amdgcn_mfma_f32_16x16x32_bf16(wv, af, accV[mi], 0, 0, 0);
                }
            }
            const int nidx = m >= Npts ? m - Npts : m;
            const float sw = sens[nidx];
            #pragma unroll
            for (int mi = 0; mi < 4; mi++) {
                const int wr0 = wbase + mi * 16 + l4 * 4;
                const f4 bK = *(const f4*)(bk + wr0);
                const f4 bV = *(const f4*)(bv + wr0);
                *(ushort4*)(Kt + (size_t)m * CDIM + wr0) = packbf((accK[mi] + bK) * sw);
                *(ushort4*)(Vt + (size_t)m * CDIM + wr0) = packbf((accV[mi] + bV) * sw);
            }
        }
    }
}

// Phase A: per point gather 16 K rows, dot, softmax -> 16 probs.
// Q / probs streams nontemporal: keep L3 for the K gather set.
__global__ __launch_bounds__(256, 4)
void attn_score(const ushort* __restrict__ Qb, const ushort* __restrict__ Kt,
                const int* __restrict__ knn, float* __restrict__ probs, int Npts)
{
    const int gi = blockIdx.x * 4 + (threadIdx.x >> 6);   // [0, 2*Npts)
    const int lane = threadIdx.x & 63;
    const int base = gi >= Npts ? Npts : 0;
    const int n    = gi - base;
    if (n >= Npts) return;

    const u16x4 qh = __builtin_nontemporal_load(
        (const u16x4*)(Qb + (size_t)gi * CDIM + lane * 4));

    const int ns = __builtin_amdgcn_readfirstlane(n);
    const int* ki = knn + ns * KNN;
    int idxs[KNN];
    #pragma unroll
    for (int j = 0; j < KNN; j++) idxs[j] = ki[j];

    ushort4 kr[KNN];
    #pragma unroll
    for (int j = 0; j < KNN; j++)
        kr[j] = *(const ushort4*)(Kt + (size_t)(base + idxs[j]) * CDIM + lane * 4);
    __builtin_amdgcn_sched_barrier(0);

    f4 q;
    q[0] = bf2f(qh[0]); q[1] = bf2f(qh[1]); q[2] = bf2f(qh[2]); q[3] = bf2f(qh[3]);

    float d[KNN];
    #pragma unroll
    for (int j = 0; j < KNN; j++)
        d[j] = q[0] * bf2f(kr[j].x) + q[1] * bf2f(kr[j].y)
             + q[2] * bf2f(kr[j].z) + q[3] * bf2f(kr[j].w);

    #pragma unroll
    for (int m = 1; m < 64; m <<= 1) {
        #pragma unroll
        for (int j = 0; j < KNN; j++) d[j] += __shfl_xor(d[j], m, 64);
    }

    float mx = -1e30f;
    #pragma unroll
    for (int j = 0; j < KNN; j++) { d[j] *= 0.0625f; mx = fmaxf(mx, d[j]); }
    float s = 0.f;
    #pragma unroll
    for (int j = 0; j < KNN; j++) { d[j] = __expf(d[j] - mx); s += d[j]; }
    const float inv = 1.f / s;

    if (lane == 0) {
        float* pp = probs + (size_t)gi * KNN;
        __builtin_nontemporal_store(
            (f4){d[0] * inv, d[1] * inv, d[2] * inv, d[3] * inv}, (f4*)pp);
        __builtin_nontemporal_store(
            (f4){d[4] * inv, d[5] * inv, d[6] * inv, d[7] * inv}, (f4*)(pp + 4));
        __builtin_nontemporal_store(
            (f4){d[8] * inv, d[9] * inv, d[10] * inv, d[11] * inv}, (f4*)(pp + 8));
        __builtin_nontemporal_store(
            (f4){d[12] * inv, d[13] * inv, d[14] * inv, d[15] * inv}, (f4*)(pp + 12));
    }
}

// Phase B: per point gather 16 V rows, weighted sum, residual + LayerNorm.
__global__ __launch_bounds__(256, 4)
void attn_pv(const ushort* __restrict__ Qb, const ushort* __restrict__ Vt,
             const int* __restrict__ knn, const float* __restrict__ probs,
             float* __restrict__ Out,
             const float* __restrict__ ln_g, const float* __restrict__ ln_b,
             int Npts)
{
    const int gi = blockIdx.x * 4 + (threadIdx.x >> 6);
    const int lane = threadIdx.x & 63;
    const int base = gi >= Npts ? Npts : 0;
    const int n    = gi - base;
    if (n >= Npts) return;

    const int ns = __builtin_amdgcn_readfirstlane(n);
    const int gs = __builtin_amdgcn_readfirstlane(gi);
    const int* ki = knn + ns * KNN;
    int idxs[KNN];
    #pragma unroll
    for (int j = 0; j < KNN; j++) idxs[j] = ki[j];

    ushort4 vr[KNN];
    #pragma unroll
    for (int j = 0; j < KNN; j++)
        vr[j] = *(const ushort4*)(Vt + (size_t)(base + idxs[j]) * CDIM + lane * 4);
    __builtin_amdgcn_sched_barrier(0);

    // wave-uniform prob reads -> scalar loads
    const float* pp = probs + (size_t)gs * KNN;
    float p[KNN];
    #pragma unroll
    for (int j = 0; j < KNN; j++) p[j] = pp[j];

    const u16x4 qh = __builtin_nontemporal_load(
        (const u16x4*)(Qb + (size_t)gi * CDIM + lane * 4));
    f4 q;
    q[0] = bf2f(qh[0]); q[1] = bf2f(qh[1]); q[2] = bf2f(qh[2]); q[3] = bf2f(qh[3]);

    f4 o = (f4){0.f, 0.f, 0.f, 0.f};
    #pragma unroll
    for (int j = 0; j < KNN; j++) {
        o[0] += p[j] * bf2f(vr[j].x); o[1] += p[j] * bf2f(vr[j].y);
        o[2] += p[j] * bf2f(vr[j].z); o[3] += p[j] * bf2f(vr[j].w);
    }

    f4 x = o + q;

    float ssum = x[0] + x[1] + x[2] + x[3];
    #pragma unroll
    for (int m = 1; m < 64; m <<= 1) ssum += __shfl_xor(ssum, m, 64);
    const float mu = ssum * (1.f / 256.f);

    f4 e;
    e[0] = x[0] - mu; e[1] = x[1] - mu; e[2] = x[2] - mu; e[3] = x[3] - mu;
    float vsum = e[0] * e[0] + e[1] * e[1] + e[2] * e[2] + e[3] * e[3];
    #pragma unroll
    for (int m = 1; m < 64; m <<= 1) vsum += __shfl_xor(vsum, m, 64);
    const float rstd = rsqrtf(vsum * (1.f / 256.f) + 1e-5f);

    const f4 g  = *(const f4*)(ln_g + lane * 4);
    const f4 bb = *(const f4*)(ln_b + lane * 4);
    f4 outv;
    outv[0] = e[0] * rstd * g[0] + bb[0];
    outv[1] = e[1] * rstd * g[1] + bb[1];
    outv[2] = e[2] * rstd * g[2] + bb[2];
    outv[3] = e[3] * rstd * g[3] + bb[3];
    __builtin_nontemporal_store(outv, (f4*)(Out + (size_t)gi * CDIM + lane * 4));
}

extern "C" void kernel_launch(void* const* d_in, const int* in_sizes, int n_in,
                              void* d_out, int out_size, void* d_ws, size_t ws_size,
                              hipStream_t stream)
{
    const float* q_feat  = (const float*)d_in[0];
    const float* kv_feat = (const float*)d_in[1];
    const int*   knn     = (const int*)d_in[2];
    const float* sens    = (const float*)d_in[3];
    const float* Wq_w    = (const float*)d_in[4];
    const float* Wq_b    = (const float*)d_in[5];
    const float* Wk_w    = (const float*)d_in[6];
    const float* Wk_b    = (const float*)d_in[7];
    const float* Wv_w    = (const float*)d_in[8];
    const float* Wv_b    = (const float*)d_in[9];
    const float* ln_g    = (const float*)d_in[10];
    const float* ln_b    = (const float*)d_in[11];

    const int Npts = in_sizes[3];              // N = 50000
    const int M    = in_sizes[0] / CDIM;       // B*N = 100000
    const int ngroups = (M + 255) / 256;       // 391 groups of 256 rows

    ushort* Qb  = (ushort*)d_ws;               // [M][256] bf16 (51.2 MB)
    ushort* Kt  = Qb + (size_t)M * CDIM;       // [M][256] bf16 (51.2 MB)
    ushort* Vt  = Kt + (size_t)M * CDIM;       // [M][256] bf16 (51.2 MB)
    float* probs = (float*)(Vt + (size_t)M * CDIM);  // [M][16] f32 (6.4 MB)

    const int nwg = 4 * NCH;                   // 256 blocks, 1/CU
    uni_proj<<<nwg, 1024, 0, stream>>>(q_feat, kv_feat, Wq_w, Wk_w, Wv_w,
                                       Wq_b, Wk_b, Wv_b, sens,
                                       Qb, Kt, Vt, M, Npts, nwg, ngroups);

    const int nblk = (2 * Npts + 3) / 4;
    attn_score<<<nblk, 256, 0, stream>>>(Qb, Kt, knn, probs, Npts);
    attn_pv<<<nblk, 256, 0, stream>>>(Qb, Vt, knn, probs, (float*)d_out,
                                      ln_g, ln_b, Npts);
}